// Round 1
// baseline (749.777 us; speedup 1.0000x reference)
//
#include <hip/hip_runtime.h>
#include <hip/hip_bf16.h>

#define IN_C 116
#define HEADS 4
#define OUT_C 16
#define OUT_DIM 64
#define NEG_SLOPE 0.2f
#define BN_EPS 1e-5f

// ---- order-preserving float<->uint encoding for atomicMax-based segment max ----
__device__ __forceinline__ unsigned encf(float f) {
    unsigned u = __float_as_uint(f);
    return (u & 0x80000000u) ? ~u : (u | 0x80000000u);
}
__device__ __forceinline__ float decf(unsigned u) {
    unsigned b = (u & 0x80000000u) ? (u & 0x7FFFFFFFu) : ~u;
    return __uint_as_float(b);
}

// ---- Kernel A: xl = x@Wl+bl, xr = x@Wr+br, xres = x@Wres+bres ----
// block: 256 threads = 4 waves; wave t handles nodes bn+t, bn+t+4, bn+t+8, bn+t+12
__global__ __launch_bounds__(256) void lin3_kernel(
    const float* __restrict__ x,
    const float* __restrict__ Wl, const float* __restrict__ bl,
    const float* __restrict__ Wr, const float* __restrict__ br,
    const float* __restrict__ Wres, const float* __restrict__ bres,
    float* __restrict__ xl, float* __restrict__ xr, float* __restrict__ xres,
    int N)
{
    __shared__ float xs[16][IN_C];
    const int bn = blockIdx.x * 16;
    const int tid = threadIdx.x;
    for (int i = tid; i < 16 * IN_C; i += 256) {
        int n = i / IN_C, k = i - n * IN_C;
        int gn = bn + n;
        xs[n][k] = (gn < N) ? x[(size_t)gn * IN_C + k] : 0.f;
    }
    __syncthreads();
    const int j = tid & 63;
    const int t = tid >> 6;

    float al[4] = {0, 0, 0, 0}, ar[4] = {0, 0, 0, 0}, as_[4] = {0, 0, 0, 0};
    for (int k = 0; k < IN_C; ++k) {
        float wl = Wl[k * OUT_DIM + j];
        float wr = Wr[k * OUT_DIM + j];
        float ws = Wres[k * OUT_DIM + j];
        #pragma unroll
        for (int u = 0; u < 4; ++u) {
            float xv = xs[t + 4 * u][k];
            al[u] += xv * wl;
            ar[u] += xv * wr;
            as_[u] += xv * ws;
        }
    }
    float blj = bl[j], brj = br[j], bsj = bres[j];
    #pragma unroll
    for (int u = 0; u < 4; ++u) {
        int gn = bn + t + 4 * u;
        if (gn < N) {
            xl[(size_t)gn * OUT_DIM + j] = al[u] + blj;
            xr[(size_t)gn * OUT_DIM + j] = ar[u] + brj;
            xres[(size_t)gn * OUT_DIM + j] = as_[u] + bsj;
        }
    }
}

// ---- Kernel B1: per (edge, head) logits + segment max over dst ----
__global__ __launch_bounds__(256) void edge_logits_kernel(
    const int* __restrict__ ei, const float* __restrict__ ea,
    const float* __restrict__ xl, const float* __restrict__ xr,
    const float* __restrict__ We, const float* __restrict__ att,
    float* __restrict__ logits, unsigned* __restrict__ mmax,
    int E, int Etot)
{
    int idx = blockIdx.x * 256 + threadIdx.x;
    if (idx >= Etot * HEADS) return;
    int e = idx >> 2, h = idx & 3;
    int src, dst; float eav;
    if (e < E) { src = ei[e]; dst = ei[E + e]; eav = ea[e]; }
    else       { src = e - E; dst = e - E;    eav = 1.0f; }

    const float4* xl4 = (const float4*)(xl + (size_t)src * OUT_DIM + h * OUT_C);
    const float4* xr4 = (const float4*)(xr + (size_t)dst * OUT_DIM + h * OUT_C);
    const float4* We4 = (const float4*)(We + h * OUT_C);
    const float4* at4 = (const float4*)(att + h * OUT_C);

    float logit = 0.f;
    #pragma unroll
    for (int q = 0; q < 4; ++q) {
        float4 a = xl4[q], b = xr4[q], w = We4[q], tt = at4[q];
        float s;
        s = a.x + b.x + eav * w.x; logit += tt.x * (s > 0.f ? s : NEG_SLOPE * s);
        s = a.y + b.y + eav * w.y; logit += tt.y * (s > 0.f ? s : NEG_SLOPE * s);
        s = a.z + b.z + eav * w.z; logit += tt.z * (s > 0.f ? s : NEG_SLOPE * s);
        s = a.w + b.w + eav * w.w; logit += tt.w * (s > 0.f ? s : NEG_SLOPE * s);
    }
    logits[idx] = logit;
    atomicMax(&mmax[dst * HEADS + h], encf(logit));
}

// ---- Kernel B2: ex = exp(logit - max); denom += ex; hacc[dst] += ex * xl[src] ----
__global__ __launch_bounds__(256) void edge_scatter_kernel(
    const int* __restrict__ ei,
    const float* __restrict__ xl, const float* __restrict__ logits,
    const unsigned* __restrict__ mmax,
    float* __restrict__ denom, float* __restrict__ hacc,
    int E, int Etot)
{
    long long idx = (long long)blockIdx.x * 256 + threadIdx.x;
    if (idx >= (long long)Etot * OUT_DIM) return;
    int e = (int)(idx >> 6), j = (int)(idx & 63), h = j >> 4;
    int src, dst;
    if (e < E) { src = ei[e]; dst = ei[E + e]; }
    else       { src = e - E; dst = e - E; }

    float logit = logits[e * HEADS + h];
    float mval = decf(mmax[dst * HEADS + h]);
    float ex = __expf(logit - mval);
    if ((j & 15) == 0) atomicAdd(&denom[dst * HEADS + h], ex);
    atomicAdd(&hacc[(size_t)dst * OUT_DIM + j], ex * xl[(size_t)src * OUT_DIM + j]);
}

// ---- Kernel C1: h = hacc/denom + gat_bias; accumulate channel sum/sumsq ----
__global__ __launch_bounds__(256) void finalize_stats_kernel(
    float* __restrict__ hacc, const float* __restrict__ denom,
    const float* __restrict__ gat_bias,
    float* __restrict__ chansum, float* __restrict__ chansumsq, int N)
{
    const int j = threadIdx.x & 63;
    const int t = threadIdx.x >> 6;
    const int h = j >> 4;
    float s = 0.f, ss = 0.f;
    const float bj = gat_bias[j];
    for (int n = blockIdx.x * 4 + t; n < N; n += gridDim.x * 4) {
        float d = denom[n * HEADS + h];
        float v = hacc[(size_t)n * OUT_DIM + j] / d + bj;
        hacc[(size_t)n * OUT_DIM + j] = v;
        s += v; ss += v * v;
    }
    __shared__ float ls[4][64], lss[4][64];
    ls[t][j] = s; lss[t][j] = ss;
    __syncthreads();
    if (t == 0) {
        float S = ls[0][j] + ls[1][j] + ls[2][j] + ls[3][j];
        float SS = lss[0][j] + lss[1][j] + lss[2][j] + lss[3][j];
        atomicAdd(&chansum[j], S);
        atomicAdd(&chansumsq[j], SS);
    }
}

// ---- Kernel C2: mu, rsig from channel sums ----
__global__ void bn_params_kernel(const float* __restrict__ chansum,
                                 const float* __restrict__ chansumsq,
                                 float* __restrict__ mu, float* __restrict__ rsig,
                                 int N)
{
    int j = threadIdx.x;
    float invN = 1.0f / (float)N;
    float m = chansum[j] * invN;
    float var = chansumsq[j] * invN - m * m;
    mu[j] = m;
    rsig[j] = rsqrtf(var + BN_EPS);
}

// ---- Kernel D: BN + residual + pooled sums/counts ----
__global__ __launch_bounds__(256) void bn_res_pool_kernel(
    const float* __restrict__ hraw, const float* __restrict__ xres,
    const float* __restrict__ mu, const float* __restrict__ rsig,
    const float* __restrict__ gamma, const float* __restrict__ beta,
    const int* __restrict__ batch,
    float* __restrict__ pooled, float* __restrict__ cnt, int N)
{
    long long tid = (long long)blockIdx.x * 256 + threadIdx.x;
    int n = (int)(tid >> 6), j = (int)(tid & 63);
    if (n >= N) return;
    int g = batch[n];
    float v = gamma[j] * (hraw[(size_t)n * OUT_DIM + j] - mu[j]) * rsig[j] + beta[j]
            + xres[(size_t)n * OUT_DIM + j];
    atomicAdd(&pooled[g * OUT_DIM + j], v);
    if (j == 0) atomicAdd(&cnt[g], 1.0f);
}

// ---- Kernel E: pooled mean -> relu(pW1+b1) -> W2+b2 ----
__global__ __launch_bounds__(64) void mlp_kernel(
    const float* __restrict__ pooled, const float* __restrict__ cnt,
    const float* __restrict__ W1, const float* __restrict__ b1,
    const float* __restrict__ W2, const float* __restrict__ b2,
    float* __restrict__ out, int G)
{
    int g = blockIdx.x, j = threadIdx.x;
    __shared__ float ps[64];
    float c = cnt[g];
    c = c > 1.0f ? c : 1.0f;
    ps[j] = pooled[g * OUT_DIM + j] / c;
    __syncthreads();
    float z = b1[j];
    for (int k = 0; k < 64; ++k) z += ps[k] * W1[k * 64 + j];
    z = z > 0.f ? z : 0.f;
    float o0 = z * W2[j * 2 + 0];
    float o1 = z * W2[j * 2 + 1];
    #pragma unroll
    for (int off = 32; off > 0; off >>= 1) {
        o0 += __shfl_down(o0, off);
        o1 += __shfl_down(o1, off);
    }
    if (j == 0) {
        out[g * 2 + 0] = o0 + b2[0];
        out[g * 2 + 1] = o1 + b2[1];
    }
}

extern "C" void kernel_launch(void* const* d_in, const int* in_sizes, int n_in,
                              void* d_out, int out_size, void* d_ws, size_t ws_size,
                              hipStream_t stream) {
    const float* x        = (const float*)d_in[0];
    const int*   ei       = (const int*)d_in[1];
    const float* ea       = (const float*)d_in[2];
    const int*   batch    = (const int*)d_in[3];
    const float* Wl       = (const float*)d_in[4];
    const float* bl       = (const float*)d_in[5];
    const float* Wr       = (const float*)d_in[6];
    const float* br       = (const float*)d_in[7];
    const float* We       = (const float*)d_in[8];
    const float* att      = (const float*)d_in[9];
    const float* gat_bias = (const float*)d_in[10];
    const float* gamma    = (const float*)d_in[11];
    const float* beta     = (const float*)d_in[12];
    const float* Wres     = (const float*)d_in[13];
    const float* bres     = (const float*)d_in[14];
    const float* W1       = (const float*)d_in[15];
    const float* b1       = (const float*)d_in[16];
    const float* W2       = (const float*)d_in[17];
    const float* b2       = (const float*)d_in[18];
    float* out = (float*)d_out;

    const int N = in_sizes[0] / IN_C;       // 50000
    const int E = in_sizes[1] / 2;          // 800000
    const int G = out_size / 2;             // 100
    const int Etot = E + N;                 // edges + self loops

    // ---- workspace layout (f32 elements) ----
    float* ws = (float*)d_ws;
    float* xl     = ws;
    float* xr     = xl + (size_t)N * OUT_DIM;
    float* xres   = xr + (size_t)N * OUT_DIM;
    float* logits = xres + (size_t)N * OUT_DIM;
    float* zbase  = logits + (size_t)Etot * HEADS;   // start of zeroed region
    float* hacc   = zbase;
    unsigned* mmax = (unsigned*)(hacc + (size_t)N * OUT_DIM);
    float* denom  = (float*)mmax + (size_t)N * HEADS;
    float* chansum   = denom + (size_t)N * HEADS;
    float* chansumsq = chansum + 64;
    float* mu        = chansumsq + 64;
    float* rsig      = mu + 64;
    float* pooled    = rsig + 64;
    float* cnt       = pooled + (size_t)G * OUT_DIM;
    float* zend      = cnt + G;

    size_t zero_bytes = (size_t)(zend - zbase) * sizeof(float);
    hipMemsetAsync(zbase, 0, zero_bytes, stream);
    // note: mmax zeroed = encoded minimum (below enc(-inf)); every node has a
    // self loop so every dst's max gets written in pass B1.

    // A: the three input projections
    lin3_kernel<<<(N + 15) / 16, 256, 0, stream>>>(
        x, Wl, bl, Wr, br, Wres, bres, xl, xr, xres, N);

    // B1: logits + segment max
    {
        long long tot = (long long)Etot * HEADS;
        int blocks = (int)((tot + 255) / 256);
        edge_logits_kernel<<<blocks, 256, 0, stream>>>(
            ei, ea, xl, xr, We, att, logits, mmax, E, Etot);
    }

    // B2: exp + denom + weighted scatter
    {
        long long tot = (long long)Etot * OUT_DIM;
        int blocks = (int)((tot + 255) / 256);
        edge_scatter_kernel<<<blocks, 256, 0, stream>>>(
            ei, xl, logits, mmax, denom, hacc, E, Etot);
    }

    // C1: finalize h (divide by denom, add bias) + BN channel stats
    finalize_stats_kernel<<<256, 256, 0, stream>>>(
        hacc, denom, gat_bias, chansum, chansumsq, N);

    // C2: mu / rsig
    bn_params_kernel<<<1, 64, 0, stream>>>(chansum, chansumsq, mu, rsig, N);

    // D: BN + residual + pooled segment sums
    {
        long long tot = (long long)N * OUT_DIM;
        int blocks = (int)((tot + 255) / 256);
        bn_res_pool_kernel<<<blocks, 256, 0, stream>>>(
            hacc, xres, mu, rsig, gamma, beta, batch, pooled, cnt, N);
    }

    // E: final 2-layer MLP per graph
    mlp_kernel<<<G, 64, 0, stream>>>(pooled, cnt, W1, b1, W2, b2, out, G);
}

// Round 2
// 381.827 us; speedup vs baseline: 1.9637x; 1.9637x over previous
//
#include <hip/hip_runtime.h>
#include <hip/hip_bf16.h>

#define IN_C 116
#define HEADS 4
#define OUT_C 16
#define OUT_DIM 64
#define NEG_SLOPE 0.2f
#define BN_EPS 1e-5f
#define SCAN_B 256

// ---- Kernel A: xl = x@Wl+bl, xr = x@Wr+br, xres = x@Wres+bres ----
__global__ __launch_bounds__(256) void lin3_kernel(
    const float* __restrict__ x,
    const float* __restrict__ Wl, const float* __restrict__ bl,
    const float* __restrict__ Wr, const float* __restrict__ br,
    const float* __restrict__ Wres, const float* __restrict__ bres,
    float* __restrict__ xl, float* __restrict__ xr, float* __restrict__ xres,
    int N)
{
    __shared__ float xs[16][IN_C];
    const int bn = blockIdx.x * 16;
    const int tid = threadIdx.x;
    for (int i = tid; i < 16 * IN_C; i += 256) {
        int n = i / IN_C, k = i - n * IN_C;
        int gn = bn + n;
        xs[n][k] = (gn < N) ? x[(size_t)gn * IN_C + k] : 0.f;
    }
    __syncthreads();
    const int j = tid & 63;
    const int t = tid >> 6;

    float al[4] = {0, 0, 0, 0}, ar[4] = {0, 0, 0, 0}, as_[4] = {0, 0, 0, 0};
    for (int k = 0; k < IN_C; ++k) {
        float wl = Wl[k * OUT_DIM + j];
        float wr = Wr[k * OUT_DIM + j];
        float ws = Wres[k * OUT_DIM + j];
        #pragma unroll
        for (int u = 0; u < 4; ++u) {
            float xv = xs[t + 4 * u][k];
            al[u] += xv * wl;
            ar[u] += xv * wr;
            as_[u] += xv * ws;
        }
    }
    float blj = bl[j], brj = br[j], bsj = bres[j];
    #pragma unroll
    for (int u = 0; u < 4; ++u) {
        int gn = bn + t + 4 * u;
        if (gn < N) {
            xl[(size_t)gn * OUT_DIM + j] = al[u] + blj;
            xr[(size_t)gn * OUT_DIM + j] = ar[u] + brj;
            xres[(size_t)gn * OUT_DIM + j] = as_[u] + bsj;
        }
    }
}

// ---- CSR build: degree histogram (deg pre-zeroed; self loops included) ----
__global__ __launch_bounds__(256) void deg_kernel(
    const int* __restrict__ ei, int* __restrict__ deg, int E, int Etot)
{
    int e = blockIdx.x * 256 + threadIdx.x;
    if (e >= Etot) return;
    int dst = (e < E) ? ei[E + e] : e - E;
    atomicAdd(&deg[dst], 1);
}

// ---- scan1: per-block exclusive scan of deg -> rowcur; block totals -> bsum ----
__global__ __launch_bounds__(SCAN_B) void scan1_kernel(
    const int* __restrict__ deg, int* __restrict__ rowcur,
    int* __restrict__ bsum, int N)
{
    __shared__ int ls[SCAN_B];
    int i = blockIdx.x * SCAN_B + threadIdx.x;
    int v = (i < N) ? deg[i] : 0;
    ls[threadIdx.x] = v;
    __syncthreads();
    for (int off = 1; off < SCAN_B; off <<= 1) {
        int add = (threadIdx.x >= off) ? ls[threadIdx.x - off] : 0;
        __syncthreads();
        ls[threadIdx.x] += add;
        __syncthreads();
    }
    if (i < N) rowcur[i] = ls[threadIdx.x] - v;   // exclusive within block
    if (threadIdx.x == SCAN_B - 1) bsum[blockIdx.x] = ls[SCAN_B - 1];
}

// ---- scan2: single-block exclusive scan of bsum (requires nb <= 256) ----
__global__ __launch_bounds__(SCAN_B) void scan2_kernel(int* __restrict__ bsum, int nb)
{
    __shared__ int ls[SCAN_B];
    int v = (threadIdx.x < nb) ? bsum[threadIdx.x] : 0;
    ls[threadIdx.x] = v;
    __syncthreads();
    for (int off = 1; off < SCAN_B; off <<= 1) {
        int add = (threadIdx.x >= off) ? ls[threadIdx.x - off] : 0;
        __syncthreads();
        ls[threadIdx.x] += add;
        __syncthreads();
    }
    if (threadIdx.x < nb) bsum[threadIdx.x] = ls[threadIdx.x] - v; // exclusive
}

// ---- scan3: add block offsets -> rowcur[n] = global start of node n's list ----
__global__ __launch_bounds__(SCAN_B) void scan3_kernel(
    int* __restrict__ rowcur, const int* __restrict__ bsum, int N)
{
    int i = blockIdx.x * SCAN_B + threadIdx.x;
    if (i < N) rowcur[i] += bsum[blockIdx.x];
}

// ---- fill: scatter edges into CSR slots; rowcur[n] becomes END of n's list ----
__global__ __launch_bounds__(256) void fill_kernel(
    const int* __restrict__ ei, const float* __restrict__ ea,
    int* __restrict__ rowcur, int* __restrict__ esrc, float* __restrict__ eattr,
    int E, int Etot)
{
    int e = blockIdx.x * 256 + threadIdx.x;
    if (e >= Etot) return;
    int src, dst; float av;
    if (e < E) { src = ei[e]; dst = ei[E + e]; av = ea[e]; }
    else       { src = e - E; dst = e - E;    av = 1.0f; }
    int p = atomicAdd(&rowcur[dst], 1);
    esrc[p] = src;
    eattr[p] = av;
}

// ---- gather: full GATv2 per node. One wave per node, lane j = channel.
// Online softmax (running max m, denom, weighted acc) -> no float atomics.
// Writes hout IN PLACE over xr (each thread reads its own xr[n,j] first).
__global__ __launch_bounds__(256) void gat_gather_kernel(
    const int* __restrict__ rowcur, const int* __restrict__ esrc,
    const float* __restrict__ eattr,
    const float* __restrict__ xl, float* __restrict__ xr_hout,
    const float* __restrict__ We, const float* __restrict__ att,
    const float* __restrict__ gat_bias, int N)
{
    const int j = threadIdx.x & 63;
    const int t = threadIdx.x >> 6;
    const int n = blockIdx.x * 4 + t;
    if (n >= N) return;

    const float xrj  = xr_hout[(size_t)n * OUT_DIM + j];
    const float Wej  = We[j];
    const float attj = att[j];

    int p0 = (n == 0) ? 0 : rowcur[n - 1];
    int p1 = rowcur[n];
    p0 = __builtin_amdgcn_readfirstlane(p0);
    p1 = __builtin_amdgcn_readfirstlane(p1);

    float m = -1e30f, den = 0.f, acc = 0.f;
    for (int p = p0; p < p1; ++p) {
        int src  = esrc[p];
        float av = eattr[p];
        float xlv = xl[(size_t)src * OUT_DIM + j];
        float s = xlv + xrj + av * Wej;
        s = s > 0.f ? s : NEG_SLOPE * s;
        float pl = attj * s;
        pl += __shfl_xor(pl, 1);
        pl += __shfl_xor(pl, 2);
        pl += __shfl_xor(pl, 4);
        pl += __shfl_xor(pl, 8);
        // online softmax update (all 16 lanes of a head group agree on pl)
        float mnew = pl > m ? pl : m;
        float corr = __expf(m - mnew);
        float ex   = __expf(pl - mnew);
        den = den * corr + ex;
        acc = acc * corr + ex * xlv;
        m = mnew;
    }
    xr_hout[(size_t)n * OUT_DIM + j] = acc / den + gat_bias[j];
}

// ---- stats: channel sum/sumsq for BN (few blocks -> low atomic pressure) ----
__global__ __launch_bounds__(256) void stats_kernel(
    const float* __restrict__ h, float* __restrict__ chansum,
    float* __restrict__ chansumsq, int N)
{
    const int j = threadIdx.x & 63;
    const int t = threadIdx.x >> 6;
    float s = 0.f, ss = 0.f;
    for (int n = blockIdx.x * 4 + t; n < N; n += gridDim.x * 4) {
        float v = h[(size_t)n * OUT_DIM + j];
        s += v; ss += v * v;
    }
    __shared__ float ls[4][64], lss[4][64];
    ls[t][j] = s; lss[t][j] = ss;
    __syncthreads();
    if (t == 0) {
        atomicAdd(&chansum[j],   ls[0][j] + ls[1][j] + ls[2][j] + ls[3][j]);
        atomicAdd(&chansumsq[j], lss[0][j] + lss[1][j] + lss[2][j] + lss[3][j]);
    }
}

// ---- mu, rsig ----
__global__ void bn_params_kernel(const float* __restrict__ chansum,
                                 const float* __restrict__ chansumsq,
                                 float* __restrict__ mu, float* __restrict__ rsig,
                                 int N)
{
    int j = threadIdx.x;
    float invN = 1.0f / (float)N;
    float m = chansum[j] * invN;
    float var = chansumsq[j] * invN - m * m;
    mu[j] = m;
    rsig[j] = rsqrtf(var + BN_EPS);
}

// ---- BN + residual + pool. batch is SORTED: run-length accumulate, flush one
// atomic per (graph-segment, channel) per thread. 256 nodes per block. ----
__global__ __launch_bounds__(256) void bn_res_pool_kernel(
    const float* __restrict__ hraw, const float* __restrict__ xres,
    const float* __restrict__ mu, const float* __restrict__ rsig,
    const float* __restrict__ gamma, const float* __restrict__ beta,
    const int* __restrict__ batch,
    float* __restrict__ pooled, float* __restrict__ cnt, int N)
{
    const int j = threadIdx.x & 63;
    const int t = threadIdx.x >> 6;
    const int base = blockIdx.x * 256;
    const float gj = gamma[j], bj = beta[j], mj = mu[j], rj = rsig[j];

    float sum = 0.f, c = 0.f;
    int gcur = -1;
    for (int i = t; i < 256; i += 4) {
        int n = base + i;
        if (n >= N) break;
        int g = batch[n];
        if (g != gcur) {
            if (gcur >= 0) {
                atomicAdd(&pooled[gcur * OUT_DIM + j], sum);
                if (j == 0) atomicAdd(&cnt[gcur], c);
            }
            sum = 0.f; c = 0.f; gcur = g;
        }
        float v = gj * (hraw[(size_t)n * OUT_DIM + j] - mj) * rj + bj
                + xres[(size_t)n * OUT_DIM + j];
        sum += v; c += 1.f;
    }
    if (gcur >= 0) {
        atomicAdd(&pooled[gcur * OUT_DIM + j], sum);
        if (j == 0) atomicAdd(&cnt[gcur], c);
    }
}

// ---- final MLP per graph ----
__global__ __launch_bounds__(64) void mlp_kernel(
    const float* __restrict__ pooled, const float* __restrict__ cnt,
    const float* __restrict__ W1, const float* __restrict__ b1,
    const float* __restrict__ W2, const float* __restrict__ b2,
    float* __restrict__ out, int G)
{
    int g = blockIdx.x, j = threadIdx.x;
    __shared__ float ps[64];
    float c = cnt[g];
    c = c > 1.0f ? c : 1.0f;
    ps[j] = pooled[g * OUT_DIM + j] / c;
    __syncthreads();
    float z = b1[j];
    for (int k = 0; k < 64; ++k) z += ps[k] * W1[k * 64 + j];
    z = z > 0.f ? z : 0.f;
    float o0 = z * W2[j * 2 + 0];
    float o1 = z * W2[j * 2 + 1];
    #pragma unroll
    for (int off = 32; off > 0; off >>= 1) {
        o0 += __shfl_down(o0, off);
        o1 += __shfl_down(o1, off);
    }
    if (j == 0) {
        out[g * 2 + 0] = o0 + b2[0];
        out[g * 2 + 1] = o1 + b2[1];
    }
}

extern "C" void kernel_launch(void* const* d_in, const int* in_sizes, int n_in,
                              void* d_out, int out_size, void* d_ws, size_t ws_size,
                              hipStream_t stream) {
    const float* x        = (const float*)d_in[0];
    const int*   ei       = (const int*)d_in[1];
    const float* ea       = (const float*)d_in[2];
    const int*   batch    = (const int*)d_in[3];
    const float* Wl       = (const float*)d_in[4];
    const float* bl       = (const float*)d_in[5];
    const float* Wr       = (const float*)d_in[6];
    const float* br       = (const float*)d_in[7];
    const float* We       = (const float*)d_in[8];
    const float* att      = (const float*)d_in[9];
    const float* gat_bias = (const float*)d_in[10];
    const float* gamma    = (const float*)d_in[11];
    const float* beta     = (const float*)d_in[12];
    const float* Wres     = (const float*)d_in[13];
    const float* bres     = (const float*)d_in[14];
    const float* W1       = (const float*)d_in[15];
    const float* b1       = (const float*)d_in[16];
    const float* W2       = (const float*)d_in[17];
    const float* b2       = (const float*)d_in[18];
    float* out = (float*)d_out;

    const int N = in_sizes[0] / IN_C;       // 50000
    const int E = in_sizes[1] / 2;          // 800000
    const int G = out_size / 2;             // 100
    const int Etot = E + N;                 // edges + self loops

    // ---- workspace layout ----
    float* ws = (float*)d_ws;
    float* xl      = ws;                               // N*64
    float* xr      = xl + (size_t)N * OUT_DIM;         // N*64 (becomes hout)
    float* xres    = xr + (size_t)N * OUT_DIM;         // N*64
    float* eattr   = xres + (size_t)N * OUT_DIM;       // Etot
    int*   esrc    = (int*)(eattr + Etot);             // Etot
    int*   rowcur  = esrc + Etot;                      // N
    int*   bsum    = rowcur + N;                       // 256
    int*   deg     = bsum + 256;                       // N   <-- zero region start
    float* chansum   = (float*)(deg + N);              // 64
    float* chansumsq = chansum + 64;                   // 64
    float* pooled    = chansumsq + 64;                 // G*64
    float* cnt       = pooled + (size_t)G * OUT_DIM;   // G   <-- zero region end
    float* mu        = cnt + G;                        // 64
    float* rsig      = mu + 64;                        // 64

    size_t zero_bytes = (size_t)((char*)(cnt + G) - (char*)deg);
    hipMemsetAsync(deg, 0, zero_bytes, stream);

    const int nb = (N + SCAN_B - 1) / SCAN_B;          // 196 <= 256 required by scan2

    // A: the three input projections
    lin3_kernel<<<(N + 15) / 16, 256, 0, stream>>>(
        x, Wl, bl, Wr, br, Wres, bres, xl, xr, xres, N);

    // CSR build by dst
    deg_kernel<<<(Etot + 255) / 256, 256, 0, stream>>>(ei, deg, E, Etot);
    scan1_kernel<<<nb, SCAN_B, 0, stream>>>(deg, rowcur, bsum, N);
    scan2_kernel<<<1, SCAN_B, 0, stream>>>(bsum, nb);
    scan3_kernel<<<nb, SCAN_B, 0, stream>>>(rowcur, bsum, N);
    fill_kernel<<<(Etot + 255) / 256, 256, 0, stream>>>(
        ei, ea, rowcur, esrc, eattr, E, Etot);

    // Full GATv2 aggregation, atomic-free (hout written over xr)
    gat_gather_kernel<<<(N + 3) / 4, 256, 0, stream>>>(
        rowcur, esrc, eattr, xl, xr, We, att, gat_bias, N);

    // BN stats -> params
    stats_kernel<<<256, 256, 0, stream>>>(xr, chansum, chansumsq, N);
    bn_params_kernel<<<1, 64, 0, stream>>>(chansum, chansumsq, mu, rsig, N);

    // BN + residual + segmented pool
    bn_res_pool_kernel<<<(N + 255) / 256, 256, 0, stream>>>(
        xr, xres, mu, rsig, gamma, beta, batch, pooled, cnt, N);

    // final MLP
    mlp_kernel<<<G, 64, 0, stream>>>(pooled, cnt, W1, b1, W2, b2, out, G);
}

// Round 3
// 342.065 us; speedup vs baseline: 2.1919x; 1.1162x over previous
//
#include <hip/hip_runtime.h>
#include <hip/hip_bf16.h>

#define IN_C 116
#define HEADS 4
#define OUT_C 16
#define OUT_DIM 64
#define NEG_SLOPE 0.2f
#define BN_EPS 1e-5f
#define SCAN_B 256

// ---- Kernel A: xl = x@Wl+bl, xr = x@Wr+br, xres = x@Wres+bres ----
__global__ __launch_bounds__(256) void lin3_kernel(
    const float* __restrict__ x,
    const float* __restrict__ Wl, const float* __restrict__ bl,
    const float* __restrict__ Wr, const float* __restrict__ br,
    const float* __restrict__ Wres, const float* __restrict__ bres,
    float* __restrict__ xl, float* __restrict__ xr, float* __restrict__ xres,
    int N)
{
    __shared__ float xs[16][IN_C];
    const int bn = blockIdx.x * 16;
    const int tid = threadIdx.x;
    for (int i = tid; i < 16 * IN_C; i += 256) {
        int n = i / IN_C, k = i - n * IN_C;
        int gn = bn + n;
        xs[n][k] = (gn < N) ? x[(size_t)gn * IN_C + k] : 0.f;
    }
    __syncthreads();
    const int j = tid & 63;
    const int t = tid >> 6;

    float al[4] = {0, 0, 0, 0}, ar[4] = {0, 0, 0, 0}, as_[4] = {0, 0, 0, 0};
    for (int k = 0; k < IN_C; ++k) {
        float wl = Wl[k * OUT_DIM + j];
        float wr = Wr[k * OUT_DIM + j];
        float ws = Wres[k * OUT_DIM + j];
        #pragma unroll
        for (int u = 0; u < 4; ++u) {
            float xv = xs[t + 4 * u][k];
            al[u] += xv * wl;
            ar[u] += xv * wr;
            as_[u] += xv * ws;
        }
    }
    float blj = bl[j], brj = br[j], bsj = bres[j];
    #pragma unroll
    for (int u = 0; u < 4; ++u) {
        int gn = bn + t + 4 * u;
        if (gn < N) {
            xl[(size_t)gn * OUT_DIM + j] = al[u] + blj;
            xr[(size_t)gn * OUT_DIM + j] = ar[u] + brj;
            xres[(size_t)gn * OUT_DIM + j] = as_[u] + bsj;
        }
    }
}

// ---- CSR build: degree histogram (deg pre-zeroed; self loops included) ----
__global__ __launch_bounds__(256) void deg_kernel(
    const int* __restrict__ ei, int* __restrict__ deg, int E, int Etot)
{
    int e = blockIdx.x * 256 + threadIdx.x;
    if (e >= Etot) return;
    int dst = (e < E) ? ei[E + e] : e - E;
    atomicAdd(&deg[dst], 1);
}

// ---- scan1: per-block exclusive scan of deg -> rowcur (block-local); totals -> bsum ----
__global__ __launch_bounds__(SCAN_B) void scan1_kernel(
    const int* __restrict__ deg, int* __restrict__ rowcur,
    int* __restrict__ bsum, int N)
{
    __shared__ int ls[SCAN_B];
    int i = blockIdx.x * SCAN_B + threadIdx.x;
    int v = (i < N) ? deg[i] : 0;
    ls[threadIdx.x] = v;
    __syncthreads();
    for (int off = 1; off < SCAN_B; off <<= 1) {
        int add = (threadIdx.x >= off) ? ls[threadIdx.x - off] : 0;
        __syncthreads();
        ls[threadIdx.x] += add;
        __syncthreads();
    }
    if (i < N) rowcur[i] = ls[threadIdx.x] - v;   // exclusive within block
    if (threadIdx.x == SCAN_B - 1) bsum[blockIdx.x] = ls[SCAN_B - 1];
}

// ---- scan2: single-block exclusive scan of bsum (requires nb <= 256) ----
__global__ __launch_bounds__(SCAN_B) void scan2_kernel(int* __restrict__ bsum, int nb)
{
    __shared__ int ls[SCAN_B];
    int v = (threadIdx.x < nb) ? bsum[threadIdx.x] : 0;
    ls[threadIdx.x] = v;
    __syncthreads();
    for (int off = 1; off < SCAN_B; off <<= 1) {
        int add = (threadIdx.x >= off) ? ls[threadIdx.x - off] : 0;
        __syncthreads();
        ls[threadIdx.x] += add;
        __syncthreads();
    }
    if (threadIdx.x < nb) bsum[threadIdx.x] = ls[threadIdx.x] - v; // exclusive
}

// ---- fill: scatter packed (src, attr) into CSR slots.
// rowcur stays BLOCK-LOCAL; global offset = bsum[dst>>8] added here.
// After fill, rowcur[n] = block-local END of n's list. ----
__global__ __launch_bounds__(256) void fill_kernel(
    const int* __restrict__ ei, const float* __restrict__ ea,
    int* __restrict__ rowcur, const int* __restrict__ bsum,
    int2* __restrict__ epack, int E, int Etot)
{
    int e = blockIdx.x * 256 + threadIdx.x;
    if (e >= Etot) return;
    int src, dst; float av;
    if (e < E) { src = ei[e]; dst = ei[E + e]; av = ea[e]; }
    else       { src = e - E; dst = e - E;    av = 1.0f; }
    int p = bsum[dst >> 8] + atomicAdd(&rowcur[dst], 1);
    epack[p] = make_int2(src, __float_as_int(av));
}

// ---- gather: full GATv2 per node. TWO nodes per wave (32 lanes each, float2
// channels per lane). Plain softmax (no max shift -- mathematically identical,
// logits are O(5) so exp() is safe in f32). Unrolled x2 for load latency.
// Writes hout IN PLACE over xr. ----
__global__ __launch_bounds__(256) void gat_gather_kernel(
    const int* __restrict__ rowcur, const int* __restrict__ bsum,
    const int2* __restrict__ epack,
    const float* __restrict__ xl, float* __restrict__ xr_hout,
    const float* __restrict__ We, const float* __restrict__ att,
    const float* __restrict__ gat_bias, int N)
{
    const int lane = threadIdx.x & 63;
    const int wv   = threadIdx.x >> 6;      // wave in block: 0..3
    const int half = lane >> 5;             // node slot within wave
    const int c    = lane & 31;             // channel-pair index (channels 2c, 2c+1)
    const int n = blockIdx.x * 8 + wv * 2 + half;
    if (n >= N) return;

    const float2 xr2 = *(const float2*)(xr_hout + (size_t)n * OUT_DIM + 2 * c);
    const float2 We2 = *(const float2*)(We + 2 * c);
    const float2 at2 = *(const float2*)(att + 2 * c);

    const int b = n >> 8;
    const int p1 = bsum[b] + rowcur[n];
    const int p0 = (n & 255) ? (bsum[b] + rowcur[n - 1]) : bsum[b];

    float den = 0.f, acc0 = 0.f, acc1 = 0.f;

#define EDGE_BODY(PP)                                                   \
    {                                                                   \
        int2 ep = epack[PP];                                            \
        int src = ep.x;                                                 \
        float av = __int_as_float(ep.y);                                \
        float2 xv = *(const float2*)(xl + (size_t)src * OUT_DIM + 2*c); \
        float s0 = xv.x + xr2.x + av * We2.x;                           \
        float s1 = xv.y + xr2.y + av * We2.y;                           \
        s0 = s0 > 0.f ? s0 : NEG_SLOPE * s0;                            \
        s1 = s1 > 0.f ? s1 : NEG_SLOPE * s1;                            \
        float pl = at2.x * s0 + at2.y * s1;                             \
        pl += __shfl_xor(pl, 1);                                        \
        pl += __shfl_xor(pl, 2);                                        \
        pl += __shfl_xor(pl, 4);                                        \
        float ex = __expf(pl);                                          \
        den += ex;                                                      \
        acc0 += ex * xv.x;                                              \
        acc1 += ex * xv.y;                                              \
    }

    int p = p0;
    while (p + 2 <= p1) {
        EDGE_BODY(p);
        EDGE_BODY(p + 1);
        p += 2;
    }
    if (p < p1) EDGE_BODY(p);
#undef EDGE_BODY

    const float2 bias2 = *(const float2*)(gat_bias + 2 * c);
    float inv = 1.0f / den;
    float2 o;
    o.x = acc0 * inv + bias2.x;
    o.y = acc1 * inv + bias2.y;
    *(float2*)(xr_hout + (size_t)n * OUT_DIM + 2 * c) = o;
}

// ---- stats: channel sum/sumsq for BN (few blocks -> low atomic pressure) ----
__global__ __launch_bounds__(256) void stats_kernel(
    const float* __restrict__ h, float* __restrict__ chansum,
    float* __restrict__ chansumsq, int N)
{
    const int j = threadIdx.x & 63;
    const int t = threadIdx.x >> 6;
    float s = 0.f, ss = 0.f;
    for (int n = blockIdx.x * 4 + t; n < N; n += gridDim.x * 4) {
        float v = h[(size_t)n * OUT_DIM + j];
        s += v; ss += v * v;
    }
    __shared__ float ls[4][64], lss[4][64];
    ls[t][j] = s; lss[t][j] = ss;
    __syncthreads();
    if (t == 0) {
        atomicAdd(&chansum[j],   ls[0][j] + ls[1][j] + ls[2][j] + ls[3][j]);
        atomicAdd(&chansumsq[j], lss[0][j] + lss[1][j] + lss[2][j] + lss[3][j]);
    }
}

// ---- mu, rsig ----
__global__ void bn_params_kernel(const float* __restrict__ chansum,
                                 const float* __restrict__ chansumsq,
                                 float* __restrict__ mu, float* __restrict__ rsig,
                                 int N)
{
    int j = threadIdx.x;
    float invN = 1.0f / (float)N;
    float m = chansum[j] * invN;
    float var = chansumsq[j] * invN - m * m;
    mu[j] = m;
    rsig[j] = rsqrtf(var + BN_EPS);
}

// ---- BN + residual + pool. batch is SORTED: run-length accumulate, flush one
// atomic per (graph-segment, channel) per thread. 256 nodes per block. ----
__global__ __launch_bounds__(256) void bn_res_pool_kernel(
    const float* __restrict__ hraw, const float* __restrict__ xres,
    const float* __restrict__ mu, const float* __restrict__ rsig,
    const float* __restrict__ gamma, const float* __restrict__ beta,
    const int* __restrict__ batch,
    float* __restrict__ pooled, float* __restrict__ cnt, int N)
{
    const int j = threadIdx.x & 63;
    const int t = threadIdx.x >> 6;
    const int base = blockIdx.x * 256;
    const float gj = gamma[j], bj = beta[j], mj = mu[j], rj = rsig[j];

    float sum = 0.f, c = 0.f;
    int gcur = -1;
    for (int i = t; i < 256; i += 4) {
        int n = base + i;
        if (n >= N) break;
        int g = batch[n];
        if (g != gcur) {
            if (gcur >= 0) {
                atomicAdd(&pooled[gcur * OUT_DIM + j], sum);
                if (j == 0) atomicAdd(&cnt[gcur], c);
            }
            sum = 0.f; c = 0.f; gcur = g;
        }
        float v = gj * (hraw[(size_t)n * OUT_DIM + j] - mj) * rj + bj
                + xres[(size_t)n * OUT_DIM + j];
        sum += v; c += 1.f;
    }
    if (gcur >= 0) {
        atomicAdd(&pooled[gcur * OUT_DIM + j], sum);
        if (j == 0) atomicAdd(&cnt[gcur], c);
    }
}

// ---- final MLP per graph ----
__global__ __launch_bounds__(64) void mlp_kernel(
    const float* __restrict__ pooled, const float* __restrict__ cnt,
    const float* __restrict__ W1, const float* __restrict__ b1,
    const float* __restrict__ W2, const float* __restrict__ b2,
    float* __restrict__ out, int G)
{
    int g = blockIdx.x, j = threadIdx.x;
    __shared__ float ps[64];
    float c = cnt[g];
    c = c > 1.0f ? c : 1.0f;
    ps[j] = pooled[g * OUT_DIM + j] / c;
    __syncthreads();
    float z = b1[j];
    for (int k = 0; k < 64; ++k) z += ps[k] * W1[k * 64 + j];
    z = z > 0.f ? z : 0.f;
    float o0 = z * W2[j * 2 + 0];
    float o1 = z * W2[j * 2 + 1];
    #pragma unroll
    for (int off = 32; off > 0; off >>= 1) {
        o0 += __shfl_down(o0, off);
        o1 += __shfl_down(o1, off);
    }
    if (j == 0) {
        out[g * 2 + 0] = o0 + b2[0];
        out[g * 2 + 1] = o1 + b2[1];
    }
}

extern "C" void kernel_launch(void* const* d_in, const int* in_sizes, int n_in,
                              void* d_out, int out_size, void* d_ws, size_t ws_size,
                              hipStream_t stream) {
    const float* x        = (const float*)d_in[0];
    const int*   ei       = (const int*)d_in[1];
    const float* ea       = (const float*)d_in[2];
    const int*   batch    = (const int*)d_in[3];
    const float* Wl       = (const float*)d_in[4];
    const float* bl       = (const float*)d_in[5];
    const float* Wr       = (const float*)d_in[6];
    const float* br       = (const float*)d_in[7];
    const float* We       = (const float*)d_in[8];
    const float* att      = (const float*)d_in[9];
    const float* gat_bias = (const float*)d_in[10];
    const float* gamma    = (const float*)d_in[11];
    const float* beta     = (const float*)d_in[12];
    const float* Wres     = (const float*)d_in[13];
    const float* bres     = (const float*)d_in[14];
    const float* W1       = (const float*)d_in[15];
    const float* b1       = (const float*)d_in[16];
    const float* W2       = (const float*)d_in[17];
    const float* b2       = (const float*)d_in[18];
    float* out = (float*)d_out;

    const int N = in_sizes[0] / IN_C;       // 50000
    const int E = in_sizes[1] / 2;          // 800000
    const int G = out_size / 2;             // 100
    const int Etot = E + N;                 // edges + self loops

    // ---- workspace layout ----
    float* ws = (float*)d_ws;
    float* xl      = ws;                               // N*64
    float* xr      = xl + (size_t)N * OUT_DIM;         // N*64 (becomes hout)
    float* xres    = xr + (size_t)N * OUT_DIM;         // N*64
    int2*  epack   = (int2*)(xres + (size_t)N * OUT_DIM); // Etot (8B aligned: 3*N*64 even)
    int*   rowcur  = (int*)(epack + Etot);             // N
    int*   bsum    = rowcur + N;                       // 256
    int*   deg     = bsum + 256;                       // N   <-- zero region start
    float* chansum   = (float*)(deg + N);              // 64
    float* chansumsq = chansum + 64;                   // 64
    float* pooled    = chansumsq + 64;                 // G*64
    float* cnt       = pooled + (size_t)G * OUT_DIM;   // G   <-- zero region end
    float* mu        = cnt + G;                        // 64
    float* rsig      = mu + 64;                        // 64

    size_t zero_bytes = (size_t)((char*)(cnt + G) - (char*)deg);
    hipMemsetAsync(deg, 0, zero_bytes, stream);

    const int nb = (N + SCAN_B - 1) / SCAN_B;          // 196 <= 256 required by scan2

    // A: the three input projections
    lin3_kernel<<<(N + 15) / 16, 256, 0, stream>>>(
        x, Wl, bl, Wr, br, Wres, bres, xl, xr, xres, N);

    // CSR build by dst (rowcur stays block-local; bsum holds block offsets)
    deg_kernel<<<(Etot + 255) / 256, 256, 0, stream>>>(ei, deg, E, Etot);
    scan1_kernel<<<nb, SCAN_B, 0, stream>>>(deg, rowcur, bsum, N);
    scan2_kernel<<<1, SCAN_B, 0, stream>>>(bsum, nb);
    fill_kernel<<<(Etot + 255) / 256, 256, 0, stream>>>(
        ei, ea, rowcur, bsum, epack, E, Etot);

    // Full GATv2 aggregation, atomic-free, 2 nodes per wave
    gat_gather_kernel<<<(N + 7) / 8, 256, 0, stream>>>(
        rowcur, bsum, epack, xl, xr, We, att, gat_bias, N);

    // BN stats -> params
    stats_kernel<<<256, 256, 0, stream>>>(xr, chansum, chansumsq, N);
    bn_params_kernel<<<1, 64, 0, stream>>>(chansum, chansumsq, mu, rsig, N);

    // BN + residual + segmented pool
    bn_res_pool_kernel<<<(N + 255) / 256, 256, 0, stream>>>(
        xr, xres, mu, rsig, gamma, beta, batch, pooled, cnt, N);

    // final MLP
    mlp_kernel<<<G, 64, 0, stream>>>(pooled, cnt, W1, b1, W2, b2, out, G);
}

// Round 6
// 327.804 us; speedup vs baseline: 2.2873x; 1.0435x over previous
//
#include <hip/hip_runtime.h>
#include <hip/hip_bf16.h>

#define IN_C 116
#define HEADS 4
#define OUT_C 16
#define OUT_DIM 64
#define NEG_SLOPE 0.2f
#define BN_EPS 1e-5f
#define SCAN_B 256
#define LIN_BM 32          // nodes per block in lin3
#define LIN_PAD 36         // padded row (words) for xsT: 16B-aligned float4 reads

// ---- Kernel A: xl = x@Wl+bl, xr = x@Wr+br, xres = x@Wres+bres ----
// 32 nodes/block. xsT[k][node] transposed tile; each wave owns 8 nodes and per
// k-step does 2x ds_read_b128 (broadcast, conflict-free) + 3 weight loads + 24 FMA.
__global__ __launch_bounds__(256) void lin3_kernel(
    const float* __restrict__ x,
    const float* __restrict__ Wl, const float* __restrict__ bl,
    const float* __restrict__ Wr, const float* __restrict__ br,
    const float* __restrict__ Wres, const float* __restrict__ bres,
    float* __restrict__ xl, float* __restrict__ xr, float* __restrict__ xres,
    int N)
{
    __shared__ float xsT[IN_C * LIN_PAD];
    const int bn = blockIdx.x * LIN_BM;
    const int tid = threadIdx.x;

    // stage x[bn..bn+31][:] transposed (k fast -> coalesced global reads)
    for (int i = tid; i < LIN_BM * IN_C; i += 256) {
        int n = i / IN_C, k = i - n * IN_C;
        int gn = bn + n;
        xsT[k * LIN_PAD + n] = (gn < N) ? x[(size_t)gn * IN_C + k] : 0.f;
    }
    __syncthreads();

    const int j = tid & 63;       // output channel
    const int t = tid >> 6;       // wave: nodes 8t..8t+7
    const int nbase = 8 * t;

    float al[8] = {0,0,0,0,0,0,0,0};
    float ar[8] = {0,0,0,0,0,0,0,0};
    float as_[8] = {0,0,0,0,0,0,0,0};

    #pragma unroll 4
    for (int k = 0; k < IN_C; ++k) {
        float4 xa = *(const float4*)&xsT[k * LIN_PAD + nbase];
        float4 xb = *(const float4*)&xsT[k * LIN_PAD + nbase + 4];
        float wl = Wl[k * OUT_DIM + j];
        float wr = Wr[k * OUT_DIM + j];
        float wsv = Wres[k * OUT_DIM + j];
        float xv[8] = {xa.x, xa.y, xa.z, xa.w, xb.x, xb.y, xb.z, xb.w};
        #pragma unroll
        for (int u = 0; u < 8; ++u) {
            al[u] += xv[u] * wl;
            ar[u] += xv[u] * wr;
            as_[u] += xv[u] * wsv;
        }
    }

    float blj = bl[j], brj = br[j], bsj = bres[j];
    #pragma unroll
    for (int u = 0; u < 8; ++u) {
        int gn = bn + nbase + u;
        if (gn < N) {
            xl[(size_t)gn * OUT_DIM + j]   = al[u] + blj;
            xr[(size_t)gn * OUT_DIM + j]   = ar[u] + brj;
            xres[(size_t)gn * OUT_DIM + j] = as_[u] + bsj;
        }
    }
}

// ---- CSR build: degree histogram (deg pre-zeroed; self loops included) ----
__global__ __launch_bounds__(256) void deg_kernel(
    const int* __restrict__ ei, int* __restrict__ deg, int E, int Etot)
{
    int e = blockIdx.x * 256 + threadIdx.x;
    if (e >= Etot) return;
    int dst = (e < E) ? ei[E + e] : e - E;
    atomicAdd(&deg[dst], 1);
}

// ---- scan1: per-block exclusive scan of deg -> rowcur (block-local); totals -> bsum ----
__global__ __launch_bounds__(SCAN_B) void scan1_kernel(
    const int* __restrict__ deg, int* __restrict__ rowcur,
    int* __restrict__ bsum, int N)
{
    __shared__ int ls[SCAN_B];
    int i = blockIdx.x * SCAN_B + threadIdx.x;
    int v = (i < N) ? deg[i] : 0;
    ls[threadIdx.x] = v;
    __syncthreads();
    for (int off = 1; off < SCAN_B; off <<= 1) {
        int add = (threadIdx.x >= off) ? ls[threadIdx.x - off] : 0;
        __syncthreads();
        ls[threadIdx.x] += add;
        __syncthreads();
    }
    if (i < N) rowcur[i] = ls[threadIdx.x] - v;   // exclusive within block
    if (threadIdx.x == SCAN_B - 1) bsum[blockIdx.x] = ls[SCAN_B - 1];
}

// ---- scan2: single-block exclusive scan of bsum (requires nb <= 256) ----
__global__ __launch_bounds__(SCAN_B) void scan2_kernel(int* __restrict__ bsum, int nb)
{
    __shared__ int ls[SCAN_B];
    int v = (threadIdx.x < nb) ? bsum[threadIdx.x] : 0;
    ls[threadIdx.x] = v;
    __syncthreads();
    for (int off = 1; off < SCAN_B; off <<= 1) {
        int add = (threadIdx.x >= off) ? ls[threadIdx.x - off] : 0;
        __syncthreads();
        ls[threadIdx.x] += add;
        __syncthreads();
    }
    if (threadIdx.x < nb) bsum[threadIdx.x] = ls[threadIdx.x] - v; // exclusive
}

// ---- fill: scatter packed (src, attr) into CSR slots.
// rowcur stays BLOCK-LOCAL; global offset = bsum[dst>>8] added here. ----
__global__ __launch_bounds__(256) void fill_kernel(
    const int* __restrict__ ei, const float* __restrict__ ea,
    int* __restrict__ rowcur, const int* __restrict__ bsum,
    int2* __restrict__ epack, int E, int Etot)
{
    int e = blockIdx.x * 256 + threadIdx.x;
    if (e >= Etot) return;
    int src, dst; float av;
    if (e < E) { src = ei[e]; dst = ei[E + e]; av = ea[e]; }
    else       { src = e - E; dst = e - E;    av = 1.0f; }
    int p = bsum[dst >> 8] + atomicAdd(&rowcur[dst], 1);
    epack[p] = make_int2(src, __float_as_int(av));
}

// ---- gather: full GATv2 per node. TWO nodes per wave (32 lanes each, float2
// channels per lane). Plain softmax (no max shift -- mathematically identical,
// logits are O(5) so exp() is safe in f32). Unrolled x4 for load latency.
// Writes hout IN PLACE over xr. ----
__global__ __launch_bounds__(256) void gat_gather_kernel(
    const int* __restrict__ rowcur, const int* __restrict__ bsum,
    const int2* __restrict__ epack,
    const float* __restrict__ xl, float* __restrict__ xr_hout,
    const float* __restrict__ We, const float* __restrict__ att,
    const float* __restrict__ gat_bias, int N)
{
    const int lane = threadIdx.x & 63;
    const int wv   = threadIdx.x >> 6;      // wave in block: 0..3
    const int half = lane >> 5;             // node slot within wave
    const int c    = lane & 31;             // channel-pair index (channels 2c, 2c+1)
    const int n = blockIdx.x * 8 + wv * 2 + half;
    if (n >= N) return;

    const float2 xr2 = *(const float2*)(xr_hout + (size_t)n * OUT_DIM + 2 * c);
    const float2 We2 = *(const float2*)(We + 2 * c);
    const float2 at2 = *(const float2*)(att + 2 * c);

    const int b = n >> 8;
    const int p1 = bsum[b] + rowcur[n];
    const int p0 = (n & 255) ? (bsum[b] + rowcur[n - 1]) : bsum[b];

    float den = 0.f, acc0 = 0.f, acc1 = 0.f;

#define EDGE_BODY(PP)                                                   \
    {                                                                   \
        int2 ep = epack[PP];                                            \
        int src = ep.x;                                                 \
        float av = __int_as_float(ep.y);                                \
        float2 xv = *(const float2*)(xl + (size_t)src * OUT_DIM + 2*c); \
        float s0 = xv.x + xr2.x + av * We2.x;                           \
        float s1 = xv.y + xr2.y + av * We2.y;                           \
        s0 = s0 > 0.f ? s0 : NEG_SLOPE * s0;                            \
        s1 = s1 > 0.f ? s1 : NEG_SLOPE * s1;                            \
        float pl = at2.x * s0 + at2.y * s1;                             \
        pl += __shfl_xor(pl, 1);                                        \
        pl += __shfl_xor(pl, 2);                                        \
        pl += __shfl_xor(pl, 4);                                        \
        float ex = __expf(pl);                                          \
        den += ex;                                                      \
        acc0 += ex * xv.x;                                              \
        acc1 += ex * xv.y;                                              \
    }

    int p = p0;
    while (p + 4 <= p1) {
        EDGE_BODY(p);
        EDGE_BODY(p + 1);
        EDGE_BODY(p + 2);
        EDGE_BODY(p + 3);
        p += 4;
    }
    while (p < p1) { EDGE_BODY(p); ++p; }
#undef EDGE_BODY

    const float2 bias2 = *(const float2*)(gat_bias + 2 * c);
    float inv = 1.0f / den;
    float2 o;
    o.x = acc0 * inv + bias2.x;
    o.y = acc1 * inv + bias2.y;
    *(float2*)(xr_hout + (size_t)n * OUT_DIM + 2 * c) = o;
}

// ---- stats: channel sum/sumsq for BN (few blocks -> low atomic pressure) ----
__global__ __launch_bounds__(256) void stats_kernel(
    const float* __restrict__ h, float* __restrict__ chansum,
    float* __restrict__ chansumsq, int N)
{
    const int j = threadIdx.x & 63;
    const int t = threadIdx.x >> 6;
    float s = 0.f, ss = 0.f;
    for (int n = blockIdx.x * 4 + t; n < N; n += gridDim.x * 4) {
        float v = h[(size_t)n * OUT_DIM + j];
        s += v; ss += v * v;
    }
    __shared__ float ls[4][64], lss[4][64];
    ls[t][j] = s; lss[t][j] = ss;
    __syncthreads();
    if (t == 0) {
        atomicAdd(&chansum[j],   ls[0][j] + ls[1][j] + ls[2][j] + ls[3][j]);
        atomicAdd(&chansumsq[j], lss[0][j] + lss[1][j] + lss[2][j] + lss[3][j]);
    }
}

// ---- BN (params computed inline from channel sums) + residual + pool.
// batch is SORTED: run-length accumulate, flush one atomic per segment. ----
__global__ __launch_bounds__(256) void bn_res_pool_kernel(
    const float* __restrict__ hraw, const float* __restrict__ xres,
    const float* __restrict__ chansum, const float* __restrict__ chansumsq,
    const float* __restrict__ gamma, const float* __restrict__ beta,
    const int* __restrict__ batch,
    float* __restrict__ pooled, float* __restrict__ cnt, int N)
{
    const int j = threadIdx.x & 63;
    const int t = threadIdx.x >> 6;
    const int base = blockIdx.x * 256;
    const float invN = 1.0f / (float)N;
    const float mj = chansum[j] * invN;
    const float var = chansumsq[j] * invN - mj * mj;
    const float rj = rsqrtf(var + BN_EPS);
    const float gj = gamma[j], bj = beta[j];

    float sum = 0.f, c = 0.f;
    int gcur = -1;
    for (int i = t; i < 256; i += 4) {
        int n = base + i;
        if (n >= N) break;
        int g = batch[n];
        if (g != gcur) {
            if (gcur >= 0) {
                atomicAdd(&pooled[gcur * OUT_DIM + j], sum);
                if (j == 0) atomicAdd(&cnt[gcur], c);
            }
            sum = 0.f; c = 0.f; gcur = g;
        }
        float v = gj * (hraw[(size_t)n * OUT_DIM + j] - mj) * rj + bj
                + xres[(size_t)n * OUT_DIM + j];
        sum += v; c += 1.f;
    }
    if (gcur >= 0) {
        atomicAdd(&pooled[gcur * OUT_DIM + j], sum);
        if (j == 0) atomicAdd(&cnt[gcur], c);
    }
}

// ---- final MLP per graph ----
__global__ __launch_bounds__(64) void mlp_kernel(
    const float* __restrict__ pooled, const float* __restrict__ cnt,
    const float* __restrict__ W1, const float* __restrict__ b1,
    const float* __restrict__ W2, const float* __restrict__ b2,
    float* __restrict__ out, int G)
{
    int g = blockIdx.x, j = threadIdx.x;
    __shared__ float ps[64];
    float c = cnt[g];
    c = c > 1.0f ? c : 1.0f;
    ps[j] = pooled[g * OUT_DIM + j] / c;
    __syncthreads();
    float z = b1[j];
    for (int k = 0; k < 64; ++k) z += ps[k] * W1[k * 64 + j];
    z = z > 0.f ? z : 0.f;
    float o0 = z * W2[j * 2 + 0];
    float o1 = z * W2[j * 2 + 1];
    #pragma unroll
    for (int off = 32; off > 0; off >>= 1) {
        o0 += __shfl_down(o0, off);
        o1 += __shfl_down(o1, off);
    }
    if (j == 0) {
        out[g * 2 + 0] = o0 + b2[0];
        out[g * 2 + 1] = o1 + b2[1];
    }
}

extern "C" void kernel_launch(void* const* d_in, const int* in_sizes, int n_in,
                              void* d_out, int out_size, void* d_ws, size_t ws_size,
                              hipStream_t stream) {
    const float* x        = (const float*)d_in[0];
    const int*   ei       = (const int*)d_in[1];
    const float* ea       = (const float*)d_in[2];
    const int*   batch    = (const int*)d_in[3];
    const float* Wl       = (const float*)d_in[4];
    const float* bl       = (const float*)d_in[5];
    const float* Wr       = (const float*)d_in[6];
    const float* br       = (const float*)d_in[7];
    const float* We       = (const float*)d_in[8];
    const float* att      = (const float*)d_in[9];
    const float* gat_bias = (const float*)d_in[10];
    const float* gamma    = (const float*)d_in[11];
    const float* beta     = (const float*)d_in[12];
    const float* Wres     = (const float*)d_in[13];
    const float* bres     = (const float*)d_in[14];
    const float* W1       = (const float*)d_in[15];
    const float* b1       = (const float*)d_in[16];
    const float* W2       = (const float*)d_in[17];
    const float* b2       = (const float*)d_in[18];
    float* out = (float*)d_out;

    const int N = in_sizes[0] / IN_C;       // 50000
    const int E = in_sizes[1] / 2;          // 800000
    const int G = out_size / 2;             // 100
    const int Etot = E + N;                 // edges + self loops

    // ---- workspace layout ----
    float* ws = (float*)d_ws;
    float* xl      = ws;                               // N*64
    float* xr      = xl + (size_t)N * OUT_DIM;         // N*64 (becomes hout)
    float* xres    = xr + (size_t)N * OUT_DIM;         // N*64
    int2*  epack   = (int2*)(xres + (size_t)N * OUT_DIM); // Etot
    int*   rowcur  = (int*)(epack + Etot);             // N
    int*   bsum    = rowcur + N;                       // 256
    int*   deg     = bsum + 256;                       // N   <-- zero region start
    float* chansum   = (float*)(deg + N);              // 64
    float* chansumsq = chansum + 64;                   // 64
    float* pooled    = chansumsq + 64;                 // G*64
    float* cnt       = pooled + (size_t)G * OUT_DIM;   // G   <-- zero region end

    size_t zero_bytes = (size_t)((char*)(cnt + G) - (char*)deg);
    hipMemsetAsync(deg, 0, zero_bytes, stream);

    const int nb = (N + SCAN_B - 1) / SCAN_B;          // 196 <= 256 required by scan2

    // A: the three input projections
    lin3_kernel<<<(N + LIN_BM - 1) / LIN_BM, 256, 0, stream>>>(
        x, Wl, bl, Wr, br, Wres, bres, xl, xr, xres, N);

    // CSR build by dst (rowcur stays block-local; bsum holds block offsets)
    deg_kernel<<<(Etot + 255) / 256, 256, 0, stream>>>(ei, deg, E, Etot);
    scan1_kernel<<<nb, SCAN_B, 0, stream>>>(deg, rowcur, bsum, N);
    scan2_kernel<<<1, SCAN_B, 0, stream>>>(bsum, nb);
    fill_kernel<<<(Etot + 255) / 256, 256, 0, stream>>>(
        ei, ea, rowcur, bsum, epack, E, Etot);

    // Full GATv2 aggregation, atomic-free, 2 nodes per wave
    gat_gather_kernel<<<(N + 7) / 8, 256, 0, stream>>>(
        rowcur, bsum, epack, xl, xr, We, att, gat_bias, N);

    // BN stats
    stats_kernel<<<256, 256, 0, stream>>>(xr, chansum, chansumsq, N);

    // BN + residual + segmented pool (BN params derived inline)
    bn_res_pool_kernel<<<(N + 255) / 256, 256, 0, stream>>>(
        xr, xres, chansum, chansumsq, gamma, beta, batch, pooled, cnt, N);

    // final MLP
    mlp_kernel<<<G, 64, 0, stream>>>(pooled, cnt, W1, b1, W2, b2, out, G);
}

// Round 8
// 315.528 us; speedup vs baseline: 2.3763x; 1.0389x over previous
//
#include <hip/hip_runtime.h>
#include <hip/hip_bf16.h>

#define IN_C 116
#define HEADS 4
#define OUT_C 16
#define OUT_DIM 64
#define NEG_SLOPE 0.2f
#define BN_EPS 1e-5f
#define SCAN_B 256
#define LIN_BM 32          // nodes per block in lin3
#define LIN_PAD 36         // padded row (words) for xsT: 16B-aligned float4 reads

// ---- Kernel A: xl = x@Wl+bl, xr = x@Wr+br, xres = x@Wres+bres
//      + FUSED deg histogram over real edges (grid-stride; atomic latency
//        hides under other blocks' FMA issue). ----
__global__ __launch_bounds__(256) void lin3_deg_kernel(
    const float* __restrict__ x,
    const float* __restrict__ Wl, const float* __restrict__ bl,
    const float* __restrict__ Wr, const float* __restrict__ br,
    const float* __restrict__ Wres, const float* __restrict__ bres,
    float* __restrict__ xl, float* __restrict__ xr, float* __restrict__ xres,
    const int* __restrict__ ei, int* __restrict__ deg, int E,
    int N)
{
    __shared__ float xsT[IN_C * LIN_PAD];
    const int bn = blockIdx.x * LIN_BM;
    const int tid = threadIdx.x;

    // stage x[bn..bn+31][:] transposed (k fast -> coalesced global reads)
    for (int i = tid; i < LIN_BM * IN_C; i += 256) {
        int n = i / IN_C, k = i - n * IN_C;
        int gn = bn + n;
        xsT[k * LIN_PAD + n] = (gn < N) ? x[(size_t)gn * IN_C + k] : 0.f;
    }
    __syncthreads();

    const int j = tid & 63;       // output channel
    const int t = tid >> 6;       // wave: nodes 8t..8t+7
    const int nbase = 8 * t;

    float al[8] = {0,0,0,0,0,0,0,0};
    float ar[8] = {0,0,0,0,0,0,0,0};
    float as_[8] = {0,0,0,0,0,0,0,0};

    #pragma unroll 4
    for (int k = 0; k < IN_C; ++k) {
        float4 xa = *(const float4*)&xsT[k * LIN_PAD + nbase];
        float4 xb = *(const float4*)&xsT[k * LIN_PAD + nbase + 4];
        float wl = Wl[k * OUT_DIM + j];
        float wr = Wr[k * OUT_DIM + j];
        float wsv = Wres[k * OUT_DIM + j];
        float xv[8] = {xa.x, xa.y, xa.z, xa.w, xb.x, xb.y, xb.z, xb.w};
        #pragma unroll
        for (int u = 0; u < 8; ++u) {
            al[u] += xv[u] * wl;
            ar[u] += xv[u] * wr;
            as_[u] += xv[u] * wsv;
        }
    }

    float blj = bl[j], brj = br[j], bsj = bres[j];
    #pragma unroll
    for (int u = 0; u < 8; ++u) {
        int gn = bn + nbase + u;
        if (gn < N) {
            xl[(size_t)gn * OUT_DIM + j]   = al[u] + blj;
            xr[(size_t)gn * OUT_DIM + j]   = ar[u] + brj;
            xres[(size_t)gn * OUT_DIM + j] = as_[u] + bsj;
        }
    }

    // fused degree histogram over REAL edges only (self loops handled in gather)
    const int stride = gridDim.x * 256;
    for (int e = blockIdx.x * 256 + tid; e < E; e += stride)
        atomicAdd(&deg[ei[E + e]], 1);
}

// ---- scan1: per-block exclusive scan of deg -> rowcur (block-local); totals -> bsum ----
__global__ __launch_bounds__(SCAN_B) void scan1_kernel(
    const int* __restrict__ deg, int* __restrict__ rowcur,
    int* __restrict__ bsum, int N)
{
    __shared__ int ls[SCAN_B];
    int i = blockIdx.x * SCAN_B + threadIdx.x;
    int v = (i < N) ? deg[i] : 0;
    ls[threadIdx.x] = v;
    __syncthreads();
    for (int off = 1; off < SCAN_B; off <<= 1) {
        int add = (threadIdx.x >= off) ? ls[threadIdx.x - off] : 0;
        __syncthreads();
        ls[threadIdx.x] += add;
        __syncthreads();
    }
    if (i < N) rowcur[i] = ls[threadIdx.x] - v;   // exclusive within block
    if (threadIdx.x == SCAN_B - 1) bsum[blockIdx.x] = ls[SCAN_B - 1];
}

// ---- scan2: single-block exclusive scan of bsum (requires nb <= 256) ----
__global__ __launch_bounds__(SCAN_B) void scan2_kernel(int* __restrict__ bsum, int nb)
{
    __shared__ int ls[SCAN_B];
    int v = (threadIdx.x < nb) ? bsum[threadIdx.x] : 0;
    ls[threadIdx.x] = v;
    __syncthreads();
    for (int off = 1; off < SCAN_B; off <<= 1) {
        int add = (threadIdx.x >= off) ? ls[threadIdx.x - off] : 0;
        __syncthreads();
        ls[threadIdx.x] += add;
        __syncthreads();
    }
    if (threadIdx.x < nb) bsum[threadIdx.x] = ls[threadIdx.x] - v; // exclusive
}

// ---- fill: scatter packed (src, attr) into CSR slots (real edges only).
// rowcur stays BLOCK-LOCAL; global offset = bsum[dst>>8] added here. ----
__global__ __launch_bounds__(256) void fill_kernel(
    const int* __restrict__ ei, const float* __restrict__ ea,
    int* __restrict__ rowcur, const int* __restrict__ bsum,
    int2* __restrict__ epack, int E)
{
    int e = blockIdx.x * 256 + threadIdx.x;
    if (e >= E) return;
    int src = ei[e];
    int dst = ei[E + e];
    float av = ea[e];
    int p = bsum[dst >> 8] + atomicAdd(&rowcur[dst], 1);
    epack[p] = make_int2(src, __float_as_int(av));
}

// ---- gather: full GATv2 per node. FOUR nodes per wave (16 lanes each, float4
// channels per lane). Self-loop term computed analytically (src=n, attr=1).
// Plain softmax (no max shift -- identical math; logits are O(5)).
// Unrolled x4. Writes hout IN PLACE over xr. ----
__global__ __launch_bounds__(256) void gat_gather_kernel(
    const int* __restrict__ rowcur, const int* __restrict__ bsum,
    const int2* __restrict__ epack,
    const float* __restrict__ xl, float* __restrict__ xr_hout,
    const float* __restrict__ We, const float* __restrict__ att,
    const float* __restrict__ gat_bias, int N)
{
    const int lane = threadIdx.x & 63;
    const int wv   = threadIdx.x >> 6;      // wave in block: 0..3
    const int g    = lane >> 4;             // node slot within wave: 0..3
    const int q    = lane & 15;             // channel-quad index (channels 4q..4q+3)
    const int n = blockIdx.x * 16 + wv * 4 + g;
    if (n >= N) return;

    const float4 xr4 = *(const float4*)(xr_hout + (size_t)n * OUT_DIM + 4 * q);
    const float4 We4 = *(const float4*)(We + 4 * q);
    const float4 at4 = *(const float4*)(att + 4 * q);

    const int b = n >> 8;
    const int p1 = bsum[b] + rowcur[n];
    const int p0 = (n & 255) ? (bsum[b] + rowcur[n - 1]) : bsum[b];

    // self-loop term: src = n, attr = 1.0
    float den, acc0, acc1, acc2, acc3;
    {
        float4 xv = *(const float4*)(xl + (size_t)n * OUT_DIM + 4 * q);
        float s0 = xv.x + xr4.x + We4.x;
        float s1 = xv.y + xr4.y + We4.y;
        float s2 = xv.z + xr4.z + We4.z;
        float s3 = xv.w + xr4.w + We4.w;
        s0 = s0 > 0.f ? s0 : NEG_SLOPE * s0;
        s1 = s1 > 0.f ? s1 : NEG_SLOPE * s1;
        s2 = s2 > 0.f ? s2 : NEG_SLOPE * s2;
        s3 = s3 > 0.f ? s3 : NEG_SLOPE * s3;
        float pl = at4.x * s0 + at4.y * s1 + at4.z * s2 + at4.w * s3;
        pl += __shfl_xor(pl, 1);
        pl += __shfl_xor(pl, 2);   // 4-lane head reduce
        float ex = __expf(pl);
        den = ex;
        acc0 = ex * xv.x; acc1 = ex * xv.y; acc2 = ex * xv.z; acc3 = ex * xv.w;
    }

#define EDGE_BODY(PP)                                                   \
    {                                                                   \
        int2 ep = epack[PP];                                            \
        int src = ep.x;                                                 \
        float av = __int_as_float(ep.y);                                \
        float4 xv = *(const float4*)(xl + (size_t)src * OUT_DIM + 4*q); \
        float s0 = xv.x + xr4.x + av * We4.x;                           \
        float s1 = xv.y + xr4.y + av * We4.y;                           \
        float s2 = xv.z + xr4.z + av * We4.z;                           \
        float s3 = xv.w + xr4.w + av * We4.w;                           \
        s0 = s0 > 0.f ? s0 : NEG_SLOPE * s0;                            \
        s1 = s1 > 0.f ? s1 : NEG_SLOPE * s1;                            \
        s2 = s2 > 0.f ? s2 : NEG_SLOPE * s2;                            \
        s3 = s3 > 0.f ? s3 : NEG_SLOPE * s3;                            \
        float pl = at4.x * s0 + at4.y * s1 + at4.z * s2 + at4.w * s3;   \
        pl += __shfl_xor(pl, 1);                                        \
        pl += __shfl_xor(pl, 2);                                        \
        float ex = __expf(pl);                                          \
        den += ex;                                                      \
        acc0 += ex * xv.x;                                              \
        acc1 += ex * xv.y;                                              \
        acc2 += ex * xv.z;                                              \
        acc3 += ex * xv.w;                                              \
    }

    int p = p0;
    while (p + 4 <= p1) {
        EDGE_BODY(p);
        EDGE_BODY(p + 1);
        EDGE_BODY(p + 2);
        EDGE_BODY(p + 3);
        p += 4;
    }
    while (p < p1) { EDGE_BODY(p); ++p; }
#undef EDGE_BODY

    const float4 bias4 = *(const float4*)(gat_bias + 4 * q);
    float inv = 1.0f / den;
    float4 o;
    o.x = acc0 * inv + bias4.x;
    o.y = acc1 * inv + bias4.y;
    o.z = acc2 * inv + bias4.z;
    o.w = acc3 * inv + bias4.w;
    *(float4*)(xr_hout + (size_t)n * OUT_DIM + 4 * q) = o;
}

// ---- stats: channel sum/sumsq for BN (few blocks -> low atomic pressure) ----
__global__ __launch_bounds__(256) void stats_kernel(
    const float* __restrict__ h, float* __restrict__ chansum,
    float* __restrict__ chansumsq, int N)
{
    const int j = threadIdx.x & 63;
    const int t = threadIdx.x >> 6;
    float s = 0.f, ss = 0.f;
    for (int n = blockIdx.x * 4 + t; n < N; n += gridDim.x * 4) {
        float v = h[(size_t)n * OUT_DIM + j];
        s += v; ss += v * v;
    }
    __shared__ float ls[4][64], lss[4][64];
    ls[t][j] = s; lss[t][j] = ss;
    __syncthreads();
    if (t == 0) {
        atomicAdd(&chansum[j],   ls[0][j] + ls[1][j] + ls[2][j] + ls[3][j]);
        atomicAdd(&chansumsq[j], lss[0][j] + lss[1][j] + lss[2][j] + lss[3][j]);
    }
}

// ---- BN (params computed inline from channel sums) + residual + pool.
// batch is SORTED: run-length accumulate, flush one atomic per segment. ----
__global__ __launch_bounds__(256) void bn_res_pool_kernel(
    const float* __restrict__ hraw, const float* __restrict__ xres,
    const float* __restrict__ chansum, const float* __restrict__ chansumsq,
    const float* __restrict__ gamma, const float* __restrict__ beta,
    const int* __restrict__ batch,
    float* __restrict__ pooled, float* __restrict__ cnt, int N)
{
    const int j = threadIdx.x & 63;
    const int t = threadIdx.x >> 6;
    const int base = blockIdx.x * 256;
    const float invN = 1.0f / (float)N;
    const float mj = chansum[j] * invN;
    const float var = chansumsq[j] * invN - mj * mj;
    const float rj = rsqrtf(var + BN_EPS);
    const float gj = gamma[j], bj = beta[j];

    float sum = 0.f, c = 0.f;
    int gcur = -1;
    for (int i = t; i < 256; i += 4) {
        int n = base + i;
        if (n >= N) break;
        int g = batch[n];
        if (g != gcur) {
            if (gcur >= 0) {
                atomicAdd(&pooled[gcur * OUT_DIM + j], sum);
                if (j == 0) atomicAdd(&cnt[gcur], c);
            }
            sum = 0.f; c = 0.f; gcur = g;
        }
        float v = gj * (hraw[(size_t)n * OUT_DIM + j] - mj) * rj + bj
                + xres[(size_t)n * OUT_DIM + j];
        sum += v; c += 1.f;
    }
    if (gcur >= 0) {
        atomicAdd(&pooled[gcur * OUT_DIM + j], sum);
        if (j == 0) atomicAdd(&cnt[gcur], c);
    }
}

// ---- final MLP per graph ----
__global__ __launch_bounds__(64) void mlp_kernel(
    const float* __restrict__ pooled, const float* __restrict__ cnt,
    const float* __restrict__ W1, const float* __restrict__ b1,
    const float* __restrict__ W2, const float* __restrict__ b2,
    float* __restrict__ out, int G)
{
    int g = blockIdx.x, j = threadIdx.x;
    __shared__ float ps[64];
    float c = cnt[g];
    c = c > 1.0f ? c : 1.0f;
    ps[j] = pooled[g * OUT_DIM + j] / c;
    __syncthreads();
    float z = b1[j];
    for (int k = 0; k < 64; ++k) z += ps[k] * W1[k * 64 + j];
    z = z > 0.f ? z : 0.f;
    float o0 = z * W2[j * 2 + 0];
    float o1 = z * W2[j * 2 + 1];
    #pragma unroll
    for (int off = 32; off > 0; off >>= 1) {
        o0 += __shfl_down(o0, off);
        o1 += __shfl_down(o1, off);
    }
    if (j == 0) {
        out[g * 2 + 0] = o0 + b2[0];
        out[g * 2 + 1] = o1 + b2[1];
    }
}

extern "C" void kernel_launch(void* const* d_in, const int* in_sizes, int n_in,
                              void* d_out, int out_size, void* d_ws, size_t ws_size,
                              hipStream_t stream) {
    const float* x        = (const float*)d_in[0];
    const int*   ei       = (const int*)d_in[1];
    const float* ea       = (const float*)d_in[2];
    const int*   batch    = (const int*)d_in[3];
    const float* Wl       = (const float*)d_in[4];
    const float* bl       = (const float*)d_in[5];
    const float* Wr       = (const float*)d_in[6];
    const float* br       = (const float*)d_in[7];
    const float* We       = (const float*)d_in[8];
    const float* att      = (const float*)d_in[9];
    const float* gat_bias = (const float*)d_in[10];
    const float* gamma    = (const float*)d_in[11];
    const float* beta     = (const float*)d_in[12];
    const float* Wres     = (const float*)d_in[13];
    const float* bres     = (const float*)d_in[14];
    const float* W1       = (const float*)d_in[15];
    const float* b1       = (const float*)d_in[16];
    const float* W2       = (const float*)d_in[17];
    const float* b2       = (const float*)d_in[18];
    float* out = (float*)d_out;

    const int N = in_sizes[0] / IN_C;       // 50000
    const int E = in_sizes[1] / 2;          // 800000
    const int G = out_size / 2;             // 100

    // ---- workspace layout ----
    float* ws = (float*)d_ws;
    float* xl      = ws;                               // N*64
    float* xr      = xl + (size_t)N * OUT_DIM;         // N*64 (becomes hout)
    float* xres    = xr + (size_t)N * OUT_DIM;         // N*64
    int2*  epack   = (int2*)(xres + (size_t)N * OUT_DIM); // E (real edges only)
    int*   rowcur  = (int*)(epack + E);                // N
    int*   bsum    = rowcur + N;                       // 256
    int*   deg     = bsum + 256;                       // N   <-- zero region start
    float* chansum   = (float*)(deg + N);              // 64
    float* chansumsq = chansum + 64;                   // 64
    float* pooled    = chansumsq + 64;                 // G*64
    float* cnt       = pooled + (size_t)G * OUT_DIM;   // G   <-- zero region end

    size_t zero_bytes = (size_t)((char*)(cnt + G) - (char*)deg);
    hipMemsetAsync(deg, 0, zero_bytes, stream);

    const int nb = (N + SCAN_B - 1) / SCAN_B;          // 196 <= 256 required by scan2

    // A: three input projections + fused degree histogram
    lin3_deg_kernel<<<(N + LIN_BM - 1) / LIN_BM, 256, 0, stream>>>(
        x, Wl, bl, Wr, br, Wres, bres, xl, xr, xres, ei, deg, E, N);

    // CSR build by dst (rowcur stays block-local; bsum holds block offsets)
    scan1_kernel<<<nb, SCAN_B, 0, stream>>>(deg, rowcur, bsum, N);
    scan2_kernel<<<1, SCAN_B, 0, stream>>>(bsum, nb);
    fill_kernel<<<(E + 255) / 256, 256, 0, stream>>>(
        ei, ea, rowcur, bsum, epack, E);

    // Full GATv2 aggregation, atomic-free, 4 nodes per wave, self-loop analytic
    gat_gather_kernel<<<(N + 15) / 16, 256, 0, stream>>>(
        rowcur, bsum, epack, xl, xr, We, att, gat_bias, N);

    // BN stats
    stats_kernel<<<256, 256, 0, stream>>>(xr, chansum, chansumsq, N);

    // BN + residual + segmented pool (BN params derived inline)
    bn_res_pool_kernel<<<(N + 255) / 256, 256, 0, stream>>>(
        xr, xres, chansum, chansumsq, gamma, beta, batch, pooled, cnt, N);

    // final MLP
    mlp_kernel<<<G, 64, 0, stream>>>(pooled, cnt, W1, b1, W2, b2, out, G);
}

// Round 9
// 307.042 us; speedup vs baseline: 2.4419x; 1.0276x over previous
//
#include <hip/hip_runtime.h>
#include <hip/hip_bf16.h>

#define IN_C 116
#define HEADS 4
#define OUT_C 16
#define OUT_DIM 64
#define NEG_SLOPE 0.2f
#define BN_EPS 1e-5f
#define LIN_BM 64          // nodes per block in lin3
#define LIN_PAD 68         // padded row (words) for xsT: 16B-aligned float4 reads
#define CAP 64             // fixed slots per node (deg ~Poisson(16); P(deg>64) ~ 1e-20)
#define OVF_CAP 4096       // overflow side list (exactness safety net)

// ---- Kernel A: xl = x@Wl+bl, xr = x@Wr+br, xres = x@Wres+bres ----
// 64 nodes/block; each wave owns 16 nodes. Per k-step: 4 uniform ds_read_b128
// (broadcast, conflict-free) + 3 weight loads + 48 FMAs.
__global__ __launch_bounds__(256) void lin3_kernel(
    const float* __restrict__ x,
    const float* __restrict__ Wl, const float* __restrict__ bl,
    const float* __restrict__ Wr, const float* __restrict__ br,
    const float* __restrict__ Wres, const float* __restrict__ bres,
    float* __restrict__ xl, float* __restrict__ xr, float* __restrict__ xres,
    int N)
{
    __shared__ float xsT[IN_C * LIN_PAD];   // 116*68*4 = 30.8 KB
    const int bn = blockIdx.x * LIN_BM;
    const int tid = threadIdx.x;

    // stage x[bn..bn+63][:] transposed (k fast -> coalesced global reads)
    for (int i = tid; i < LIN_BM * IN_C; i += 256) {
        int n = i / IN_C, k = i - n * IN_C;
        int gn = bn + n;
        xsT[k * LIN_PAD + n] = (gn < N) ? x[(size_t)gn * IN_C + k] : 0.f;
    }
    __syncthreads();

    const int j = tid & 63;       // output channel
    const int t = tid >> 6;       // wave: nodes 16t..16t+15
    const int nbase = 16 * t;

    float al[16], ar[16], as_[16];
    #pragma unroll
    for (int u = 0; u < 16; ++u) { al[u] = 0.f; ar[u] = 0.f; as_[u] = 0.f; }

    #pragma unroll 2
    for (int k = 0; k < IN_C; ++k) {
        const float* row = &xsT[k * LIN_PAD + nbase];
        float4 xa = *(const float4*)(row);
        float4 xb = *(const float4*)(row + 4);
        float4 xc = *(const float4*)(row + 8);
        float4 xd = *(const float4*)(row + 12);
        float wl  = Wl[k * OUT_DIM + j];
        float wr  = Wr[k * OUT_DIM + j];
        float wsv = Wres[k * OUT_DIM + j];
        float xv[16] = {xa.x, xa.y, xa.z, xa.w, xb.x, xb.y, xb.z, xb.w,
                        xc.x, xc.y, xc.z, xc.w, xd.x, xd.y, xd.z, xd.w};
        #pragma unroll
        for (int u = 0; u < 16; ++u) {
            al[u]  += xv[u] * wl;
            ar[u]  += xv[u] * wr;
            as_[u] += xv[u] * wsv;
        }
    }

    float blj = bl[j], brj = br[j], bsj = bres[j];
    #pragma unroll
    for (int u = 0; u < 16; ++u) {
        int gn = bn + nbase + u;
        if (gn < N) {
            xl[(size_t)gn * OUT_DIM + j]   = al[u] + blj;
            xr[(size_t)gn * OUT_DIM + j]   = ar[u] + brj;
            xres[(size_t)gn * OUT_DIM + j] = as_[u] + bsj;
        }
    }
}

// ---- fill: bucket scatter, NO deg/scan. slot via one atomic on cnt[dst];
// payload written nontemporally (skip L2 line churn). Overflow -> side list. ----
__global__ __launch_bounds__(256) void fill_kernel(
    const int* __restrict__ ei, const float* __restrict__ ea,
    int* __restrict__ cnt, unsigned long long* __restrict__ epack,
    int* __restrict__ ovf, int* __restrict__ ovf_cnt, int E)
{
    int e = blockIdx.x * 256 + threadIdx.x;
    if (e >= E) return;
    int src = ei[e];
    int dst = ei[E + e];
    float av = ea[e];
    int slot = atomicAdd(&cnt[dst], 1);
    if (slot < CAP) {
        unsigned long long v =
            ((unsigned long long)(unsigned)__float_as_uint(av) << 32) | (unsigned)src;
        __builtin_nontemporal_store(v, epack + (size_t)dst * CAP + slot);
    } else {
        int o = atomicAdd(ovf_cnt, 1);
        if (o < OVF_CAP) {
            ovf[3 * o] = src; ovf[3 * o + 1] = __float_as_int(av); ovf[3 * o + 2] = dst;
        }
    }
}

// ---- gather: full GATv2 per node. FOUR nodes per wave (16 lanes each, float4
// channels per lane). Self-loop analytic (src=n, attr=1). Plain softmax (no
// max shift -- identical math, logits O(5)). Writes hout IN PLACE over xr. ----
__global__ __launch_bounds__(256) void gat_gather_kernel(
    const int* __restrict__ cnt, const unsigned long long* __restrict__ epack,
    const int* __restrict__ ovf, const int* __restrict__ ovf_cnt,
    const float* __restrict__ xl, float* __restrict__ xr_hout,
    const float* __restrict__ We, const float* __restrict__ att,
    const float* __restrict__ gat_bias, int N)
{
    const int lane = threadIdx.x & 63;
    const int wv   = threadIdx.x >> 6;      // wave in block: 0..3
    const int g    = lane >> 4;             // node slot within wave: 0..3
    const int q    = lane & 15;             // channel-quad index (channels 4q..4q+3)
    const int n = blockIdx.x * 16 + wv * 4 + g;
    if (n >= N) return;

    const float4 xr4 = *(const float4*)(xr_hout + (size_t)n * OUT_DIM + 4 * q);
    const float4 We4 = *(const float4*)(We + 4 * q);
    const float4 at4 = *(const float4*)(att + 4 * q);

    int len = cnt[n];
    len = len < CAP ? len : CAP;
    const unsigned long long* ep = epack + (size_t)n * CAP;

    // self-loop term: src = n, attr = 1.0
    float den, acc0, acc1, acc2, acc3;
    {
        float4 xv = *(const float4*)(xl + (size_t)n * OUT_DIM + 4 * q);
        float s0 = xv.x + xr4.x + We4.x;
        float s1 = xv.y + xr4.y + We4.y;
        float s2 = xv.z + xr4.z + We4.z;
        float s3 = xv.w + xr4.w + We4.w;
        s0 = s0 > 0.f ? s0 : NEG_SLOPE * s0;
        s1 = s1 > 0.f ? s1 : NEG_SLOPE * s1;
        s2 = s2 > 0.f ? s2 : NEG_SLOPE * s2;
        s3 = s3 > 0.f ? s3 : NEG_SLOPE * s3;
        float pl = at4.x * s0 + at4.y * s1 + at4.z * s2 + at4.w * s3;
        pl += __shfl_xor(pl, 1);
        pl += __shfl_xor(pl, 2);   // 4-lane head reduce
        float ex = __expf(pl);
        den = ex;
        acc0 = ex * xv.x; acc1 = ex * xv.y; acc2 = ex * xv.z; acc3 = ex * xv.w;
    }

#define EDGE_CORE(SRC, AV)                                              \
    {                                                                   \
        int src = (SRC);                                                \
        float av = (AV);                                                \
        float4 xv = *(const float4*)(xl + (size_t)src * OUT_DIM + 4*q); \
        float s0 = xv.x + xr4.x + av * We4.x;                           \
        float s1 = xv.y + xr4.y + av * We4.y;                           \
        float s2 = xv.z + xr4.z + av * We4.z;                           \
        float s3 = xv.w + xr4.w + av * We4.w;                           \
        s0 = s0 > 0.f ? s0 : NEG_SLOPE * s0;                            \
        s1 = s1 > 0.f ? s1 : NEG_SLOPE * s1;                            \
        s2 = s2 > 0.f ? s2 : NEG_SLOPE * s2;                            \
        s3 = s3 > 0.f ? s3 : NEG_SLOPE * s3;                            \
        float pl = at4.x * s0 + at4.y * s1 + at4.z * s2 + at4.w * s3;   \
        pl += __shfl_xor(pl, 1);                                        \
        pl += __shfl_xor(pl, 2);                                        \
        float ex = __expf(pl);                                          \
        den += ex;                                                      \
        acc0 += ex * xv.x;                                              \
        acc1 += ex * xv.y;                                              \
        acc2 += ex * xv.z;                                              \
        acc3 += ex * xv.w;                                              \
    }

#define EDGE_BODY(PP)                                                   \
    {                                                                   \
        unsigned long long v = __builtin_nontemporal_load(ep + (PP));   \
        EDGE_CORE((int)(unsigned)(v & 0xffffffffull),                   \
                  __uint_as_float((unsigned)(v >> 32)));                \
    }

    int p = 0;
    while (p + 4 <= len) {
        EDGE_BODY(p);
        EDGE_BODY(p + 1);
        EDGE_BODY(p + 2);
        EDGE_BODY(p + 3);
        p += 4;
    }
    while (p < len) { EDGE_BODY(p); ++p; }

    // overflow edges (normally zero): exactness safety net
    int oc = *ovf_cnt;
    if (oc > 0) {
        oc = oc < OVF_CAP ? oc : OVF_CAP;
        for (int o = 0; o < oc; ++o) {
            if (ovf[3 * o + 2] == n)
                EDGE_CORE(ovf[3 * o], __int_as_float(ovf[3 * o + 1]));
        }
    }
#undef EDGE_BODY
#undef EDGE_CORE

    const float4 bias4 = *(const float4*)(gat_bias + 4 * q);
    float inv = 1.0f / den;
    float4 o;
    o.x = acc0 * inv + bias4.x;
    o.y = acc1 * inv + bias4.y;
    o.z = acc2 * inv + bias4.z;
    o.w = acc3 * inv + bias4.w;
    *(float4*)(xr_hout + (size_t)n * OUT_DIM + 4 * q) = o;
}

// ---- stats: channel sum/sumsq for BN (few blocks -> low atomic pressure) ----
__global__ __launch_bounds__(256) void stats_kernel(
    const float* __restrict__ h, float* __restrict__ chansum,
    float* __restrict__ chansumsq, int N)
{
    const int j = threadIdx.x & 63;
    const int t = threadIdx.x >> 6;
    float s = 0.f, ss = 0.f;
    for (int n = blockIdx.x * 4 + t; n < N; n += gridDim.x * 4) {
        float v = h[(size_t)n * OUT_DIM + j];
        s += v; ss += v * v;
    }
    __shared__ float ls[4][64], lss[4][64];
    ls[t][j] = s; lss[t][j] = ss;
    __syncthreads();
    if (t == 0) {
        atomicAdd(&chansum[j],   ls[0][j] + ls[1][j] + ls[2][j] + ls[3][j]);
        atomicAdd(&chansumsq[j], lss[0][j] + lss[1][j] + lss[2][j] + lss[3][j]);
    }
}

// ---- BN (params computed inline from channel sums) + residual + pool.
// batch is SORTED: run-length accumulate, flush one atomic per segment. ----
__global__ __launch_bounds__(256) void bn_res_pool_kernel(
    const float* __restrict__ hraw, const float* __restrict__ xres,
    const float* __restrict__ chansum, const float* __restrict__ chansumsq,
    const float* __restrict__ gamma, const float* __restrict__ beta,
    const int* __restrict__ batch,
    float* __restrict__ pooled, float* __restrict__ cnt, int N)
{
    const int j = threadIdx.x & 63;
    const int t = threadIdx.x >> 6;
    const int base = blockIdx.x * 256;
    const float invN = 1.0f / (float)N;
    const float mj = chansum[j] * invN;
    const float var = chansumsq[j] * invN - mj * mj;
    const float rj = rsqrtf(var + BN_EPS);
    const float gj = gamma[j], bj = beta[j];

    float sum = 0.f, c = 0.f;
    int gcur = -1;
    for (int i = t; i < 256; i += 4) {
        int n = base + i;
        if (n >= N) break;
        int g = batch[n];
        if (g != gcur) {
            if (gcur >= 0) {
                atomicAdd(&pooled[gcur * OUT_DIM + j], sum);
                if (j == 0) atomicAdd(&cnt[gcur], c);
            }
            sum = 0.f; c = 0.f; gcur = g;
        }
        float v = gj * (hraw[(size_t)n * OUT_DIM + j] - mj) * rj + bj
                + xres[(size_t)n * OUT_DIM + j];
        sum += v; c += 1.f;
    }
    if (gcur >= 0) {
        atomicAdd(&pooled[gcur * OUT_DIM + j], sum);
        if (j == 0) atomicAdd(&cnt[gcur], c);
    }
}

// ---- final MLP per graph ----
__global__ __launch_bounds__(64) void mlp_kernel(
    const float* __restrict__ pooled, const float* __restrict__ cnt,
    const float* __restrict__ W1, const float* __restrict__ b1,
    const float* __restrict__ W2, const float* __restrict__ b2,
    float* __restrict__ out, int G)
{
    int g = blockIdx.x, j = threadIdx.x;
    __shared__ float ps[64];
    float c = cnt[g];
    c = c > 1.0f ? c : 1.0f;
    ps[j] = pooled[g * OUT_DIM + j] / c;
    __syncthreads();
    float z = b1[j];
    for (int k = 0; k < 64; ++k) z += ps[k] * W1[k * 64 + j];
    z = z > 0.f ? z : 0.f;
    float o0 = z * W2[j * 2 + 0];
    float o1 = z * W2[j * 2 + 1];
    #pragma unroll
    for (int off = 32; off > 0; off >>= 1) {
        o0 += __shfl_down(o0, off);
        o1 += __shfl_down(o1, off);
    }
    if (j == 0) {
        out[g * 2 + 0] = o0 + b2[0];
        out[g * 2 + 1] = o1 + b2[1];
    }
}

extern "C" void kernel_launch(void* const* d_in, const int* in_sizes, int n_in,
                              void* d_out, int out_size, void* d_ws, size_t ws_size,
                              hipStream_t stream) {
    const float* x        = (const float*)d_in[0];
    const int*   ei       = (const int*)d_in[1];
    const float* ea       = (const float*)d_in[2];
    const int*   batch    = (const int*)d_in[3];
    const float* Wl       = (const float*)d_in[4];
    const float* bl       = (const float*)d_in[5];
    const float* Wr       = (const float*)d_in[6];
    const float* br       = (const float*)d_in[7];
    const float* We       = (const float*)d_in[8];
    const float* att      = (const float*)d_in[9];
    const float* gat_bias = (const float*)d_in[10];
    const float* gamma    = (const float*)d_in[11];
    const float* beta     = (const float*)d_in[12];
    const float* Wres     = (const float*)d_in[13];
    const float* bres     = (const float*)d_in[14];
    const float* W1       = (const float*)d_in[15];
    const float* b1       = (const float*)d_in[16];
    const float* W2       = (const float*)d_in[17];
    const float* b2       = (const float*)d_in[18];
    float* out = (float*)d_out;

    const int N = in_sizes[0] / IN_C;       // 50000
    const int E = in_sizes[1] / 2;          // 800000
    const int G = out_size / 2;             // 100

    // ---- workspace layout ----
    float* ws = (float*)d_ws;
    float* xl      = ws;                                   // N*64
    float* xr      = xl + (size_t)N * OUT_DIM;             // N*64 (becomes hout)
    float* xres    = xr + (size_t)N * OUT_DIM;             // N*64
    unsigned long long* epack =
        (unsigned long long*)(xres + (size_t)N * OUT_DIM); // N*CAP (25.6 MB)
    int*   cnt     = (int*)(epack + (size_t)N * CAP);      // N   <-- zero region start
    int*   ovf_cnt = cnt + N;                              // 1
    float* chansum   = (float*)(ovf_cnt + 1);              // 64
    float* chansumsq = chansum + 64;                       // 64
    float* pooled    = chansumsq + 64;                     // G*64
    float* cntg      = pooled + (size_t)G * OUT_DIM;       // G   <-- zero region end
    int*   ovf       = (int*)(cntg + G);                   // 3*OVF_CAP (not zeroed)

    size_t zero_bytes = (size_t)((char*)(cntg + G) - (char*)cnt);
    hipMemsetAsync(cnt, 0, zero_bytes, stream);

    // A: three input projections
    lin3_kernel<<<(N + LIN_BM - 1) / LIN_BM, 256, 0, stream>>>(
        x, Wl, bl, Wr, br, Wres, bres, xl, xr, xres, N);

    // bucket scatter (no deg/scan): one atomic per edge + nontemporal store
    fill_kernel<<<(E + 255) / 256, 256, 0, stream>>>(
        ei, ea, cnt, epack, ovf, ovf_cnt, E);

    // Full GATv2 aggregation, atomic-free, 4 nodes/wave, self-loop analytic
    gat_gather_kernel<<<(N + 15) / 16, 256, 0, stream>>>(
        cnt, epack, ovf, ovf_cnt, xl, xr, We, att, gat_bias, N);

    // BN stats
    stats_kernel<<<256, 256, 0, stream>>>(xr, chansum, chansumsq, N);

    // BN + residual + segmented pool (BN params derived inline)
    bn_res_pool_kernel<<<(N + 255) / 256, 256, 0, stream>>>(
        xr, xres, chansum, chansumsq, gamma, beta, batch, pooled, cntg, N);

    // final MLP
    mlp_kernel<<<G, 64, 0, stream>>>(pooled, cntg, W1, b1, W2, b2, out, G);
}

// Round 10
// 270.997 us; speedup vs baseline: 2.7667x; 1.1330x over previous
//
#include <hip/hip_runtime.h>
#include <hip/hip_bf16.h>

#define IN_C 116
#define HEADS 4
#define OUT_C 16
#define OUT_DIM 64
#define NEG_SLOPE 0.2f
#define BN_EPS 1e-5f
#define LIN_BM 32          // nodes per lin3 tile
#define LIN_PAD 36         // padded row (words) for xsT: 16B-aligned float4 reads
#define CAP 64             // fixed slots per node (deg ~Poisson(16); P(deg>64) ~ 1e-20)
#define OVF_CAP 4096       // overflow side list (exactness safety net)
#define CYCLE 40           // per 40 blocks: 32 fill (4 per partition) + 8 lin3

// ---- prep: INTERLEAVED lin3 (VALU-bound) + XCD-partitioned fill (memory-bound).
// Role by blockIdx%5: 4/5 fill, 1/5 lin3. Per 40-block cycle each dst-partition
// c (= blockIdx&7, heuristic XCD id) gets exactly 4 fill blocks and the 8
// excluded blocks (b%5==4) are one per partition -> clean rank math.
// Correctness does NOT depend on the XCD mapping (partitions are a disjoint
// cover of dst space; any block can run anywhere). ----
__global__ __launch_bounds__(256) void prep_kernel(
    const float* __restrict__ x,
    const float* __restrict__ Wl, const float* __restrict__ bl,
    const float* __restrict__ Wr, const float* __restrict__ br,
    const float* __restrict__ Wres, const float* __restrict__ bres,
    float* __restrict__ xl, float* __restrict__ xr, float* __restrict__ xres,
    const int* __restrict__ ei, const float* __restrict__ ea,
    int* __restrict__ cnt, unsigned long long* __restrict__ epack,
    int* __restrict__ ovf, int* __restrict__ ovf_cnt,
    int N, int E, int NBLIN, int FPP, int PART)
{
    __shared__ float xsT[IN_C * LIN_PAD];
    const int b = blockIdx.x;
    const int tid = threadIdx.x;

    if (b % 5 == 4) {
        // ---------------- lin3 role ----------------
        const int lb = (b / CYCLE) * 8 + (b % CYCLE) / 5;
        if (lb >= NBLIN) return;
        const int bn = lb * LIN_BM;

        for (int i = tid; i < LIN_BM * IN_C; i += 256) {
            int n = i / IN_C, k = i - n * IN_C;
            int gn = bn + n;
            xsT[k * LIN_PAD + n] = (gn < N) ? x[(size_t)gn * IN_C + k] : 0.f;
        }
        __syncthreads();

        const int j = tid & 63;       // output channel
        const int t = tid >> 6;       // wave: nodes 8t..8t+7
        const int nbase = 8 * t;

        float al[8] = {0,0,0,0,0,0,0,0};
        float ar[8] = {0,0,0,0,0,0,0,0};
        float as_[8] = {0,0,0,0,0,0,0,0};

        #pragma unroll 4
        for (int k = 0; k < IN_C; ++k) {
            float4 xa = *(const float4*)&xsT[k * LIN_PAD + nbase];
            float4 xb = *(const float4*)&xsT[k * LIN_PAD + nbase + 4];
            float wl  = Wl[k * OUT_DIM + j];
            float wr  = Wr[k * OUT_DIM + j];
            float wsv = Wres[k * OUT_DIM + j];
            float xv[8] = {xa.x, xa.y, xa.z, xa.w, xb.x, xb.y, xb.z, xb.w};
            #pragma unroll
            for (int u = 0; u < 8; ++u) {
                al[u]  += xv[u] * wl;
                ar[u]  += xv[u] * wr;
                as_[u] += xv[u] * wsv;
            }
        }

        float blj = bl[j], brj = br[j], bsj = bres[j];
        #pragma unroll
        for (int u = 0; u < 8; ++u) {
            int gn = bn + nbase + u;
            if (gn < N) {
                xl[(size_t)gn * OUT_DIM + j]   = al[u] + blj;
                xr[(size_t)gn * OUT_DIM + j]   = ar[u] + brj;
                xres[(size_t)gn * OUT_DIM + j] = as_[u] + bsj;
            }
        }
    } else {
        // ---------------- fill role (partition c = b&7) ----------------
        const int c = b & 7;
        // rank of this block within partition c's fill blocks:
        const int cyc  = b / CYCLE;
        const int jcur = ((b % CYCLE) - c) >> 3;          // 0..4 among same-c this cycle
        const int jx   = (2 * ((4 - c + 5) % 5)) % 5;     // the lin3-role j of this c
        const int q    = jcur - (jx < jcur ? 1 : 0);      // 0..3
        const int r    = cyc * 4 + q;                     // rank in [0, FPP)

        const int lo = c * PART;
        const int hi = (lo + PART < N) ? lo + PART : N;
        const unsigned span = (unsigned)(hi - lo);

        long long e0 = (long long)r * E / FPP;
        long long e1 = (long long)(r + 1) * E / FPP;

        for (long long e = e0 + tid; e < e1; e += 256) {
            int dst = ei[E + e];
            if ((unsigned)(dst - lo) >= span) continue;
            int src = ei[e];
            float av = ea[e];
            int slot = atomicAdd(&cnt[dst], 1);
            if (slot < CAP) {
                unsigned long long v =
                    ((unsigned long long)(unsigned)__float_as_uint(av) << 32) | (unsigned)src;
                epack[(size_t)dst * CAP + slot] = v;   // normal store: let L2 merge
            } else {
                int o = atomicAdd(ovf_cnt, 1);
                if (o < OVF_CAP) {
                    ovf[3 * o] = src; ovf[3 * o + 1] = __float_as_int(av); ovf[3 * o + 2] = dst;
                }
            }
        }
    }
}

// ---- gather: full GATv2 per node. FOUR nodes per wave (16 lanes each, float4
// channels per lane). Self-loop analytic (src=n, attr=1). Plain softmax (no
// max shift -- identical math, logits O(5)). Unrolled x8. In-place over xr. ----
__global__ __launch_bounds__(256) void gat_gather_kernel(
    const int* __restrict__ cnt, const unsigned long long* __restrict__ epack,
    const int* __restrict__ ovf, const int* __restrict__ ovf_cnt,
    const float* __restrict__ xl, float* __restrict__ xr_hout,
    const float* __restrict__ We, const float* __restrict__ att,
    const float* __restrict__ gat_bias, int N)
{
    const int lane = threadIdx.x & 63;
    const int wv   = threadIdx.x >> 6;      // wave in block: 0..3
    const int g    = lane >> 4;             // node slot within wave: 0..3
    const int q    = lane & 15;             // channel-quad index (channels 4q..4q+3)
    const int n = blockIdx.x * 16 + wv * 4 + g;
    if (n >= N) return;

    const float4 xr4 = *(const float4*)(xr_hout + (size_t)n * OUT_DIM + 4 * q);
    const float4 We4 = *(const float4*)(We + 4 * q);
    const float4 at4 = *(const float4*)(att + 4 * q);

    int len = cnt[n];
    len = len < CAP ? len : CAP;
    const unsigned long long* ep = epack + (size_t)n * CAP;

    // self-loop term: src = n, attr = 1.0
    float den, acc0, acc1, acc2, acc3;
    {
        float4 xv = *(const float4*)(xl + (size_t)n * OUT_DIM + 4 * q);
        float s0 = xv.x + xr4.x + We4.x;
        float s1 = xv.y + xr4.y + We4.y;
        float s2 = xv.z + xr4.z + We4.z;
        float s3 = xv.w + xr4.w + We4.w;
        s0 = s0 > 0.f ? s0 : NEG_SLOPE * s0;
        s1 = s1 > 0.f ? s1 : NEG_SLOPE * s1;
        s2 = s2 > 0.f ? s2 : NEG_SLOPE * s2;
        s3 = s3 > 0.f ? s3 : NEG_SLOPE * s3;
        float pl = at4.x * s0 + at4.y * s1 + at4.z * s2 + at4.w * s3;
        pl += __shfl_xor(pl, 1);
        pl += __shfl_xor(pl, 2);   // 4-lane head reduce
        float ex = __expf(pl);
        den = ex;
        acc0 = ex * xv.x; acc1 = ex * xv.y; acc2 = ex * xv.z; acc3 = ex * xv.w;
    }

#define EDGE_CORE(SRC, AV)                                              \
    {                                                                   \
        int src = (SRC);                                                \
        float av = (AV);                                                \
        float4 xv = *(const float4*)(xl + (size_t)src * OUT_DIM + 4*q); \
        float s0 = xv.x + xr4.x + av * We4.x;                           \
        float s1 = xv.y + xr4.y + av * We4.y;                           \
        float s2 = xv.z + xr4.z + av * We4.z;                           \
        float s3 = xv.w + xr4.w + av * We4.w;                           \
        s0 = s0 > 0.f ? s0 : NEG_SLOPE * s0;                            \
        s1 = s1 > 0.f ? s1 : NEG_SLOPE * s1;                            \
        s2 = s2 > 0.f ? s2 : NEG_SLOPE * s2;                            \
        s3 = s3 > 0.f ? s3 : NEG_SLOPE * s3;                            \
        float pl = at4.x * s0 + at4.y * s1 + at4.z * s2 + at4.w * s3;   \
        pl += __shfl_xor(pl, 1);                                        \
        pl += __shfl_xor(pl, 2);                                        \
        float ex = __expf(pl);                                          \
        den += ex;                                                      \
        acc0 += ex * xv.x;                                              \
        acc1 += ex * xv.y;                                              \
        acc2 += ex * xv.z;                                              \
        acc3 += ex * xv.w;                                              \
    }

#define EDGE_BODY(PP)                                                   \
    {                                                                   \
        unsigned long long v = __builtin_nontemporal_load(ep + (PP));   \
        EDGE_CORE((int)(unsigned)(v & 0xffffffffull),                   \
                  __uint_as_float((unsigned)(v >> 32)));                \
    }

    int p = 0;
    while (p + 8 <= len) {
        EDGE_BODY(p);     EDGE_BODY(p + 1);
        EDGE_BODY(p + 2); EDGE_BODY(p + 3);
        EDGE_BODY(p + 4); EDGE_BODY(p + 5);
        EDGE_BODY(p + 6); EDGE_BODY(p + 7);
        p += 8;
    }
    while (p + 2 <= len) { EDGE_BODY(p); EDGE_BODY(p + 1); p += 2; }
    if (p < len) EDGE_BODY(p);

    // overflow edges (normally zero): exactness safety net
    int oc = *ovf_cnt;
    if (oc > 0) {
        oc = oc < OVF_CAP ? oc : OVF_CAP;
        for (int o = 0; o < oc; ++o) {
            if (ovf[3 * o + 2] == n)
                EDGE_CORE(ovf[3 * o], __int_as_float(ovf[3 * o + 1]));
        }
    }
#undef EDGE_BODY
#undef EDGE_CORE

    const float4 bias4 = *(const float4*)(gat_bias + 4 * q);
    float inv = 1.0f / den;
    float4 o;
    o.x = acc0 * inv + bias4.x;
    o.y = acc1 * inv + bias4.y;
    o.z = acc2 * inv + bias4.z;
    o.w = acc3 * inv + bias4.w;
    *(float4*)(xr_hout + (size_t)n * OUT_DIM + 4 * q) = o;
}

// ---- stats: channel sum/sumsq for BN (few blocks -> low atomic pressure) ----
__global__ __launch_bounds__(256) void stats_kernel(
    const float* __restrict__ h, float* __restrict__ chansum,
    float* __restrict__ chansumsq, int N)
{
    const int j = threadIdx.x & 63;
    const int t = threadIdx.x >> 6;
    float s = 0.f, ss = 0.f;
    for (int n = blockIdx.x * 4 + t; n < N; n += gridDim.x * 4) {
        float v = h[(size_t)n * OUT_DIM + j];
        s += v; ss += v * v;
    }
    __shared__ float ls[4][64], lss[4][64];
    ls[t][j] = s; lss[t][j] = ss;
    __syncthreads();
    if (t == 0) {
        atomicAdd(&chansum[j],   ls[0][j] + ls[1][j] + ls[2][j] + ls[3][j]);
        atomicAdd(&chansumsq[j], lss[0][j] + lss[1][j] + lss[2][j] + lss[3][j]);
    }
}

// ---- BN (params computed inline from channel sums) + residual + pool.
// batch is SORTED: run-length accumulate, flush one atomic per segment. ----
__global__ __launch_bounds__(256) void bn_res_pool_kernel(
    const float* __restrict__ hraw, const float* __restrict__ xres,
    const float* __restrict__ chansum, const float* __restrict__ chansumsq,
    const float* __restrict__ gamma, const float* __restrict__ beta,
    const int* __restrict__ batch,
    float* __restrict__ pooled, float* __restrict__ cnt, int N)
{
    const int j = threadIdx.x & 63;
    const int t = threadIdx.x >> 6;
    const int base = blockIdx.x * 256;
    const float invN = 1.0f / (float)N;
    const float mj = chansum[j] * invN;
    const float var = chansumsq[j] * invN - mj * mj;
    const float rj = rsqrtf(var + BN_EPS);
    const float gj = gamma[j], bj = beta[j];

    float sum = 0.f, c = 0.f;
    int gcur = -1;
    for (int i = t; i < 256; i += 4) {
        int n = base + i;
        if (n >= N) break;
        int g = batch[n];
        if (g != gcur) {
            if (gcur >= 0) {
                atomicAdd(&pooled[gcur * OUT_DIM + j], sum);
                if (j == 0) atomicAdd(&cnt[gcur], c);
            }
            sum = 0.f; c = 0.f; gcur = g;
        }
        float v = gj * (hraw[(size_t)n * OUT_DIM + j] - mj) * rj + bj
                + xres[(size_t)n * OUT_DIM + j];
        sum += v; c += 1.f;
    }
    if (gcur >= 0) {
        atomicAdd(&pooled[gcur * OUT_DIM + j], sum);
        if (j == 0) atomicAdd(&cnt[gcur], c);
    }
}

// ---- final MLP per graph ----
__global__ __launch_bounds__(64) void mlp_kernel(
    const float* __restrict__ pooled, const float* __restrict__ cnt,
    const float* __restrict__ W1, const float* __restrict__ b1,
    const float* __restrict__ W2, const float* __restrict__ b2,
    float* __restrict__ out, int G)
{
    int g = blockIdx.x, j = threadIdx.x;
    __shared__ float ps[64];
    float c = cnt[g];
    c = c > 1.0f ? c : 1.0f;
    ps[j] = pooled[g * OUT_DIM + j] / c;
    __syncthreads();
    float z = b1[j];
    for (int k = 0; k < 64; ++k) z += ps[k] * W1[k * 64 + j];
    z = z > 0.f ? z : 0.f;
    float o0 = z * W2[j * 2 + 0];
    float o1 = z * W2[j * 2 + 1];
    #pragma unroll
    for (int off = 32; off > 0; off >>= 1) {
        o0 += __shfl_down(o0, off);
        o1 += __shfl_down(o1, off);
    }
    if (j == 0) {
        out[g * 2 + 0] = o0 + b2[0];
        out[g * 2 + 1] = o1 + b2[1];
    }
}

extern "C" void kernel_launch(void* const* d_in, const int* in_sizes, int n_in,
                              void* d_out, int out_size, void* d_ws, size_t ws_size,
                              hipStream_t stream) {
    const float* x        = (const float*)d_in[0];
    const int*   ei       = (const int*)d_in[1];
    const float* ea       = (const float*)d_in[2];
    const int*   batch    = (const int*)d_in[3];
    const float* Wl       = (const float*)d_in[4];
    const float* bl       = (const float*)d_in[5];
    const float* Wr       = (const float*)d_in[6];
    const float* br       = (const float*)d_in[7];
    const float* We       = (const float*)d_in[8];
    const float* att      = (const float*)d_in[9];
    const float* gat_bias = (const float*)d_in[10];
    const float* gamma    = (const float*)d_in[11];
    const float* beta     = (const float*)d_in[12];
    const float* Wres     = (const float*)d_in[13];
    const float* bres     = (const float*)d_in[14];
    const float* W1       = (const float*)d_in[15];
    const float* b1       = (const float*)d_in[16];
    const float* W2       = (const float*)d_in[17];
    const float* b2       = (const float*)d_in[18];
    float* out = (float*)d_out;

    const int N = in_sizes[0] / IN_C;       // 50000
    const int E = in_sizes[1] / 2;          // 800000
    const int G = out_size / 2;             // 100

    // ---- workspace layout ----
    float* ws = (float*)d_ws;
    float* xl      = ws;                                   // N*64
    float* xr      = xl + (size_t)N * OUT_DIM;             // N*64 (becomes hout)
    float* xres    = xr + (size_t)N * OUT_DIM;             // N*64
    unsigned long long* epack =
        (unsigned long long*)(xres + (size_t)N * OUT_DIM); // N*CAP (25.6 MB)
    int*   cnt     = (int*)(epack + (size_t)N * CAP);      // N   <-- zero region start
    int*   ovf_cnt = cnt + N;                              // 1
    float* chansum   = (float*)(ovf_cnt + 1);              // 64
    float* chansumsq = chansum + 64;                       // 64
    float* pooled    = chansumsq + 64;                     // G*64
    float* cntg      = pooled + (size_t)G * OUT_DIM;       // G   <-- zero region end
    int*   ovf       = (int*)(cntg + G);                   // 3*OVF_CAP (not zeroed)

    size_t zero_bytes = (size_t)((char*)(cntg + G) - (char*)cnt);
    hipMemsetAsync(cnt, 0, zero_bytes, stream);

    const int NBLIN = (N + LIN_BM - 1) / LIN_BM;   // 1563
    const int CYC   = (NBLIN + 7) / 8;             // 196 cycles of 40 blocks
    const int T     = CYC * CYCLE;                 // 7840 blocks total
    const int FPP   = CYC * 4;                     // fill blocks per partition (784)
    const int PART  = (N + 7) / 8;                 // dst range per partition (6250)

    // prep: lin3 (1/5 of blocks) interleaved with XCD-partitioned fill (4/5)
    prep_kernel<<<T, 256, 0, stream>>>(
        x, Wl, bl, Wr, br, Wres, bres, xl, xr, xres,
        ei, ea, cnt, epack, ovf, ovf_cnt, N, E, NBLIN, FPP, PART);

    // Full GATv2 aggregation, atomic-free, 4 nodes/wave, self-loop analytic
    gat_gather_kernel<<<(N + 15) / 16, 256, 0, stream>>>(
        cnt, epack, ovf, ovf_cnt, xl, xr, We, att, gat_bias, N);

    // BN stats
    stats_kernel<<<256, 256, 0, stream>>>(xr, chansum, chansumsq, N);

    // BN + residual + segmented pool (BN params derived inline)
    bn_res_pool_kernel<<<(N + 255) / 256, 256, 0, stream>>>(
        xr, xres, chansum, chansumsq, gamma, beta, batch, pooled, cntg, N);

    // final MLP
    mlp_kernel<<<G, 64, 0, stream>>>(pooled, cntg, W1, b1, W2, b2, out, G);
}